// Round 6
// baseline (821.070 us; speedup 1.0000x reference)
//
#include <hip/hip_runtime.h>
#include <hip/hip_bf16.h>

typedef __bf16 bf16x8 __attribute__((ext_vector_type(8)));
typedef __bf16 bf16x4 __attribute__((ext_vector_type(4)));
typedef float  f32x4  __attribute__((ext_vector_type(4)));
typedef unsigned short u16;

#define SWZ(row, byte) ((byte) ^ (((row) & 15) << 4))

__device__ __forceinline__ float bf16bits_to_f32(u16 v) {
    return __uint_as_float(((unsigned)v) << 16);
}

// ---------------------------------------------------------------------------
// prep: nf f32 -> bf16 (vectorized x4)
// ---------------------------------------------------------------------------
__global__ __launch_bounds__(256) void prep_nf(const float* __restrict__ nf,
                                               __bf16* __restrict__ nfb, int n) {
    int i = (blockIdx.x * 256 + threadIdx.x) * 4;
    if (i < n) {
        float4 v = *reinterpret_cast<const float4*>(nf + i);
        bf16x4 o;
        o[0] = (__bf16)v.x; o[1] = (__bf16)v.y; o[2] = (__bf16)v.z; o[3] = (__bf16)v.w;
        *reinterpret_cast<bf16x4*>(nfb + i) = o;
    }
}

// ---------------------------------------------------------------------------
// prep: weights -> bf16, transposed to [n][k]
// ---------------------------------------------------------------------------
__global__ __launch_bounds__(256) void prep_w(
    const float* __restrict__ eW1, const float* __restrict__ eW2,
    const float* __restrict__ nW1, const float* __restrict__ nW2,
    const float* __restrict__ u,
    __bf16* __restrict__ wt1e, __bf16* __restrict__ wt2e,
    __bf16* __restrict__ wt1n, __bf16* __restrict__ wt2n,
    __bf16* __restrict__ ub) {
    int i = blockIdx.x * 256 + threadIdx.x;
    if (i < 32768) {                       // eW1 [256][128] -> [128][256]
        int n = i >> 8, k = i & 255;
        wt1e[i] = (__bf16)eW1[k * 128 + n];
    } else if (i < 40960) {                // eW2 [128][64] -> [64][128]
        int j = i - 32768; int n = j >> 7, k = j & 127;
        wt2e[j] = (__bf16)eW2[k * 64 + n];
    } else if (i < 65536) {                // nW1 [192][128] -> [128][192]
        int j = i - 40960; int n = j / 192, k = j - n * 192;
        wt1n[j] = (__bf16)nW1[k * 128 + n];
    } else if (i < 73728) {                // nW2 [128][64] -> [64][128]
        int j = i - 65536; int n = j >> 7, k = j & 127;
        wt2n[j] = (__bf16)nW2[k * 64 + n];
    } else if (i < 73792) {
        ub[i - 73728] = (__bf16)u[i - 73728];
    }
}

// ---------------------------------------------------------------------------
// CSR build: histogram of dst, exclusive scan, per-edge CSR position.
// ---------------------------------------------------------------------------
__global__ __launch_bounds__(256) void hist_kernel(const int* __restrict__ dst,
                                                   int* __restrict__ degi, int E) {
    int e = blockIdx.x * 256 + threadIdx.x;
    if (e < E) atomicAdd(&degi[dst[e]], 1);
}

__global__ __launch_bounds__(1024) void scan_kernel(const int* __restrict__ degi,
                                                    int* __restrict__ off, int N) {
    __shared__ int sm[1024];
    const int t = threadIdx.x;
    const int chunk = (N + 1023) / 1024;
    const int base = t * chunk;
    int local = 0;
    for (int i = 0; i < chunk; ++i) {
        int idx = base + i;
        if (idx < N) local += degi[idx];
    }
    sm[t] = local;
    __syncthreads();
    for (int d = 1; d < 1024; d <<= 1) {
        int v = sm[t];
        if (t >= d) v += sm[t - d];
        __syncthreads();
        sm[t] = v;
        __syncthreads();
    }
    int run = sm[t] - local;   // exclusive prefix of this chunk
    for (int i = 0; i < chunk; ++i) {
        int idx = base + i;
        if (idx < N) { off[idx] = run; run += degi[idx]; }
    }
}

__global__ __launch_bounds__(256) void fill_kernel(const int* __restrict__ dst,
                                                   const int* __restrict__ off,
                                                   int* __restrict__ cursor,
                                                   int* __restrict__ pos, int E) {
    int e = blockIdx.x * 256 + threadIdx.x;
    if (e < E) {
        int d = dst[e];
        int slot = atomicAdd(&cursor[d], 1);
        pos[e] = off[d] + slot;
    }
}

// ---------------------------------------------------------------------------
// Edge MLP, MFMA. 64 edges/block, 4 waves x 16 edges, low-reg for occupancy.
// A-frag: row = lane&15 (edge), k = (lane>>4)*8+i
// B-frag: col = lane&15, k = (lane>>4)*8+i      (WT row-major [n][k])
// D:      col = lane&15, row = (lane>>4)*4+r
// Writes out_e (residual) + msgb in CSR order (bf16) + per-block esum partial.
// ---------------------------------------------------------------------------
__global__ __launch_bounds__(256, 3) void edge_mfma(
    const float* __restrict__ ef,
    const __bf16* __restrict__ nfb, const __bf16* __restrict__ ub,
    const __bf16* __restrict__ wt1, const __bf16* __restrict__ wt2,
    const float* __restrict__ b1, const float* __restrict__ b2,
    const int* __restrict__ src, const int* __restrict__ dst,
    const int* __restrict__ pos,
    float* __restrict__ out_e, __bf16* __restrict__ msgb,
    float* __restrict__ esum_part,
    int E)
{
    __shared__ alignas(16) char h_lds[4][4096];   // 16 rows x 256 B per wave
    __shared__ float ssum[64];
    const int tid = threadIdx.x;
    const int w = tid >> 6, l = tid & 63;
    const int lo = l & 15, hi = l >> 4;
    char* hp = h_lds[w];
    const long eb = (long)blockIdx.x * 64 + w * 16;

    long geL = eb + lo;
    const int geA = (geL < E) ? (int)geL : 0;
    const int srcA = src[geA];
    const int dstA = dst[geA];
    if (tid < 64) ssum[tid] = 0.f;

    float b1v[8];
#pragma unroll
    for (int nt = 0; nt < 8; ++nt) b1v[nt] = b1[nt * 16 + lo];
    float b2v[4];
#pragma unroll
    for (int nt = 0; nt < 4; ++nt) b2v[nt] = b2[nt * 16 + lo];

    f32x4 acc1[8] = {};
#pragma unroll
    for (int kk = 0; kk < 8; ++kk) {               // K = 256
        const int koff = (kk & 1) * 32 + hi * 8;
        bf16x8 bfr[8];
#pragma unroll
        for (int nt = 0; nt < 8; ++nt)
            bfr[nt] = *(const bf16x8*)(wt1 + (nt * 16 + lo) * 256 + kk * 32 + hi * 8);
        bf16x8 afr;
        const int sec = kk >> 1;                   // section uniform per kk
        if (sec == 0) {
            afr = *(const bf16x8*)(nfb + (size_t)srcA * 64 + koff);
        } else if (sec == 1) {
            afr = *(const bf16x8*)(nfb + (size_t)dstA * 64 + koff);
        } else if (sec == 2) {
            const float* p = ef + (size_t)geA * 64 + koff;
            float4 v0 = *(const float4*)p;
            float4 v1 = *(const float4*)(p + 4);
            bf16x8 t;
            t[0] = (__bf16)v0.x; t[1] = (__bf16)v0.y; t[2] = (__bf16)v0.z; t[3] = (__bf16)v0.w;
            t[4] = (__bf16)v1.x; t[5] = (__bf16)v1.y; t[6] = (__bf16)v1.z; t[7] = (__bf16)v1.w;
            afr = t;
        } else {
            afr = *(const bf16x8*)(ub + koff);
        }
#pragma unroll
        for (int nt = 0; nt < 8; ++nt)
            acc1[nt] = __builtin_amdgcn_mfma_f32_16x16x32_bf16(afr, bfr[nt], acc1[nt], 0, 0, 0);
    }

    // h = relu(acc1 + b1) -> per-wave LDS (bf16, XOR-swizzled rows)
#pragma unroll
    for (int nt = 0; nt < 8; ++nt) {
        int col = nt * 16 + lo;
#pragma unroll
        for (int r = 0; r < 4; ++r) {
            int row = hi * 4 + r;
            float hv = fmaxf(acc1[nt][r] + b1v[nt], 0.0f);
            *(__bf16*)(hp + SWZ(row, row * 256 + col * 2)) = (__bf16)hv;
        }
    }
    __syncthreads();

    f32x4 acc2[4] = {};
#pragma unroll
    for (int kk = 0; kk < 4; ++kk) {               // K = 128
        bf16x8 bfr2[4];
#pragma unroll
        for (int nt = 0; nt < 4; ++nt)
            bfr2[nt] = *(const bf16x8*)(wt2 + (nt * 16 + lo) * 128 + kk * 32 + hi * 8);
        int row = lo;
        bf16x8 afr = *(const bf16x8*)(hp + SWZ(row, row * 256 + (kk * 32 + hi * 8) * 2));
#pragma unroll
        for (int nt = 0; nt < 4; ++nt)
            acc2[nt] = __builtin_amdgcn_mfma_f32_16x16x32_bf16(afr, bfr2[nt], acc2[nt], 0, 0, 0);
    }

    // epilogue: residual store + CSR-ordered bf16 msg + block esum partial
    float vsum[4] = {0.f, 0.f, 0.f, 0.f};
#pragma unroll
    for (int r = 0; r < 4; ++r) {
        long ge = eb + hi * 4 + r;
        if (ge >= E) continue;
        int gei = (int)ge;
        size_t mb = (size_t)pos[gei] * 64;
#pragma unroll
        for (int nt = 0; nt < 4; ++nt) {
            int col = nt * 16 + lo;
            float msg = acc2[nt][r] + b2v[nt];
            out_e[(size_t)gei * 64 + col] = msg + ef[(size_t)gei * 64 + col];
            msgb[mb + col] = (__bf16)msg;
            vsum[nt] += msg;
        }
    }
#pragma unroll
    for (int nt = 0; nt < 4; ++nt) {
        float v = vsum[nt];
        v += __shfl_xor(v, 16);
        v += __shfl_xor(v, 32);
        if (l < 16) atomicAdd(&ssum[nt * 16 + l], v);
    }
    __syncthreads();
    if (tid < 64) esum_part[(size_t)blockIdx.x * 64 + tid] = ssum[tid];
}

// ---------------------------------------------------------------------------
// Aggregate: wave per node; msgb rows are CSR-contiguous.
// Lane layout: q = l>>4 selects row within a 4-row group, lc = l&15 covers
// 4 cols via ushort4. Fold across q with shfl_xor(16/32).
// ---------------------------------------------------------------------------
__global__ __launch_bounds__(256) void agg_kernel(
    const __bf16* __restrict__ msgb,
    const int* __restrict__ off, const int* __restrict__ degi,
    __bf16* __restrict__ aggb, int N, int n_waves)
{
    const int tid = threadIdx.x;
    const int l = tid & 63;
    const int q = l >> 4, lc = l & 15;
    const int gw = blockIdx.x * 4 + (tid >> 6);

    for (int n = gw; n < N; n += n_waves) {
        int j0 = off[n];
        int dg = degi[n];
        float s0 = 0.f, s1 = 0.f, s2 = 0.f, s3 = 0.f;
        for (int j = 0; j < dg; j += 4) {
            int row = j + q;
            if (row < dg) {
                ushort4 v = *(const ushort4*)(msgb + (size_t)(j0 + row) * 64 + lc * 4);
                s0 += bf16bits_to_f32(v.x);
                s1 += bf16bits_to_f32(v.y);
                s2 += bf16bits_to_f32(v.z);
                s3 += bf16bits_to_f32(v.w);
            }
        }
        s0 += __shfl_xor(s0, 16); s0 += __shfl_xor(s0, 32);
        s1 += __shfl_xor(s1, 16); s1 += __shfl_xor(s1, 32);
        s2 += __shfl_xor(s2, 16); s2 += __shfl_xor(s2, 32);
        s3 += __shfl_xor(s3, 16); s3 += __shfl_xor(s3, 32);
        if (l < 16) {
            float inv = 1.0f / fmaxf((float)dg, 1.0f);
            bf16x4 o;
            o[0] = (__bf16)(s0 * inv); o[1] = (__bf16)(s1 * inv);
            o[2] = (__bf16)(s2 * inv); o[3] = (__bf16)(s3 * inv);
            *(bf16x4*)(aggb + (size_t)n * 64 + lc * 4) = o;
        }
    }
}

// ---------------------------------------------------------------------------
// Node MLP, MFMA. 64 nodes/block, 4 waves x 16 nodes. K = 192 (aggb|nfb|u).
// ---------------------------------------------------------------------------
__global__ __launch_bounds__(256, 3) void node_mfma(
    const float* __restrict__ nf,
    const __bf16* __restrict__ nfb, const __bf16* __restrict__ ub,
    const __bf16* __restrict__ aggb,
    const __bf16* __restrict__ wt1, const __bf16* __restrict__ wt2,
    const float* __restrict__ b1, const float* __restrict__ b2,
    float* __restrict__ out_n, float* __restrict__ node_sum,
    int N)
{
    __shared__ alignas(16) char h_lds[4][4096];
    __shared__ float ssum[64];
    const int tid = threadIdx.x;
    const int w = tid >> 6, l = tid & 63;
    const int lo = l & 15, hi = l >> 4;
    char* hp = h_lds[w];
    const long nb = (long)blockIdx.x * 64 + w * 16;

    long gnL = nb + lo;
    const int gnA = (gnL < N) ? (int)gnL : 0;
    if (tid < 64) ssum[tid] = 0.f;

    float b1v[8];
#pragma unroll
    for (int nt = 0; nt < 8; ++nt) b1v[nt] = b1[nt * 16 + lo];
    float b2v[4];
#pragma unroll
    for (int nt = 0; nt < 4; ++nt) b2v[nt] = b2[nt * 16 + lo];

    f32x4 acc1[8] = {};
#pragma unroll
    for (int kk = 0; kk < 6; ++kk) {               // K = 192
        const int koff = (kk & 1) * 32 + hi * 8;
        bf16x8 bfr[8];
#pragma unroll
        for (int nt = 0; nt < 8; ++nt)
            bfr[nt] = *(const bf16x8*)(wt1 + (nt * 16 + lo) * 192 + kk * 32 + hi * 8);
        bf16x8 afr;
        const int sec = kk >> 1;
        if (sec == 0) {
            afr = *(const bf16x8*)(aggb + (size_t)gnA * 64 + koff);
        } else if (sec == 1) {
            afr = *(const bf16x8*)(nfb + (size_t)gnA * 64 + koff);
        } else {
            afr = *(const bf16x8*)(ub + koff);
        }
#pragma unroll
        for (int nt = 0; nt < 8; ++nt)
            acc1[nt] = __builtin_amdgcn_mfma_f32_16x16x32_bf16(afr, bfr[nt], acc1[nt], 0, 0, 0);
    }

#pragma unroll
    for (int nt = 0; nt < 8; ++nt) {
        int col = nt * 16 + lo;
#pragma unroll
        for (int r = 0; r < 4; ++r) {
            int row = hi * 4 + r;
            float hv = fmaxf(acc1[nt][r] + b1v[nt], 0.0f);
            *(__bf16*)(hp + SWZ(row, row * 256 + col * 2)) = (__bf16)hv;
        }
    }
    __syncthreads();

    f32x4 acc2[4] = {};
#pragma unroll
    for (int kk = 0; kk < 4; ++kk) {
        bf16x8 bfr2[4];
#pragma unroll
        for (int nt = 0; nt < 4; ++nt)
            bfr2[nt] = *(const bf16x8*)(wt2 + (nt * 16 + lo) * 128 + kk * 32 + hi * 8);
        int row = lo;
        bf16x8 afr = *(const bf16x8*)(hp + SWZ(row, row * 256 + (kk * 32 + hi * 8) * 2));
#pragma unroll
        for (int nt = 0; nt < 4; ++nt)
            acc2[nt] = __builtin_amdgcn_mfma_f32_16x16x32_bf16(afr, bfr2[nt], acc2[nt], 0, 0, 0);
    }

    float vsum[4] = {0.f, 0.f, 0.f, 0.f};
#pragma unroll
    for (int r = 0; r < 4; ++r) {
        long gn = nb + hi * 4 + r;
        if (gn >= N) continue;
        int gni = (int)gn;
#pragma unroll
        for (int nt = 0; nt < 4; ++nt) {
            int col = nt * 16 + lo;
            float msg = acc2[nt][r] + b2v[nt];
            out_n[(size_t)gni * 64 + col] = msg + nf[(size_t)gni * 64 + col];
            vsum[nt] += msg;
        }
    }
#pragma unroll
    for (int nt = 0; nt < 4; ++nt) {
        float v = vsum[nt];
        v += __shfl_xor(v, 16);
        v += __shfl_xor(v, 32);
        if (l < 16) atomicAdd(&ssum[nt * 16 + l], v);
    }
    __syncthreads();
    if (tid < 64) atomicAdd(&node_sum[tid], ssum[tid]);
}

// ---------------------------------------------------------------------------
// col-sum reduce: out[c] += sum_r in[r][c]
// ---------------------------------------------------------------------------
__global__ __launch_bounds__(256) void reduce_cols(const float* __restrict__ in,
                                                   float* __restrict__ out, int R) {
    int col = threadIdx.x & 63;
    int rbase = blockIdx.x * 4 + (threadIdx.x >> 6);
    float s = 0.f;
    for (int r = rbase; r < R; r += gridDim.x * 4)
        s += in[(size_t)r * 64 + col];
    __shared__ float sm[256];
    sm[threadIdx.x] = s;
    __syncthreads();
    if (threadIdx.x < 64) {
        float v = sm[threadIdx.x] + sm[threadIdx.x + 64] + sm[threadIdx.x + 128] + sm[threadIdx.x + 192];
        atomicAdd(&out[threadIdx.x], v);
    }
}

// ---------------------------------------------------------------------------
// Global MLP: single block.
// ---------------------------------------------------------------------------
__global__ __launch_bounds__(128) void global_kernel(
    const float* __restrict__ u,
    const float* __restrict__ W1, const float* __restrict__ b1,
    const float* __restrict__ W2, const float* __restrict__ b2,
    const float* __restrict__ node_sum, const float* __restrict__ edge_sum,
    float* __restrict__ out_u, int N, int E)
{
    __shared__ float gm[192];
    __shared__ float h[128];
    int tid = threadIdx.x;
    if (tid < 64) {
        gm[tid]       = node_sum[tid] / (float)N;
        gm[64 + tid]  = edge_sum[tid] / (float)E;
        gm[128 + tid] = u[tid];
    }
    __syncthreads();
    float a = b1[tid];
    for (int k = 0; k < 192; ++k) a = fmaf(gm[k], W1[k * 128 + tid], a);
    h[tid] = fmaxf(a, 0.f);
    __syncthreads();
    if (tid < 64) {
        float o = b2[tid];
        for (int k = 0; k < 128; ++k) o = fmaf(h[k], W2[k * 64 + tid], o);
        out_u[tid] = o + u[tid];
    }
}

extern "C" void kernel_launch(void* const* d_in, const int* in_sizes, int n_in,
                              void* d_out, int out_size, void* d_ws, size_t ws_size,
                              hipStream_t stream) {
    const float* nf  = (const float*)d_in[0];
    const float* ef  = (const float*)d_in[1];
    const float* u   = (const float*)d_in[2];
    const float* eW1 = (const float*)d_in[3];
    const float* eb1 = (const float*)d_in[4];
    const float* eW2 = (const float*)d_in[5];
    const float* eb2 = (const float*)d_in[6];
    const float* nW1 = (const float*)d_in[7];
    const float* nb1 = (const float*)d_in[8];
    const float* nW2 = (const float*)d_in[9];
    const float* nb2 = (const float*)d_in[10];
    const float* gW1 = (const float*)d_in[11];
    const float* gb1 = (const float*)d_in[12];
    const float* gW2 = (const float*)d_in[13];
    const float* gb2 = (const float*)d_in[14];
    const int*   src = (const int*)d_in[15];
    const int*   dst = (const int*)d_in[16];

    const int N = in_sizes[0] / 64;
    const int E = in_sizes[1] / 64;
    const int EDGE_BLOCKS = (E + 63) / 64;
    const int AGG_BLOCKS = 2048;

    char* ws = (char*)d_ws;
    size_t off_b = 0;
    auto alloc = [&](size_t bytes) { size_t c = off_b; off_b += (bytes + 255) & ~(size_t)255; return c; };

    // zeroed region first: degi | cursor | edge_sum | node_sum
    int*    degi     = (int*)(ws + alloc((size_t)N * 4));
    int*    cursor   = (int*)(ws + alloc((size_t)N * 4));
    float*  edge_sum = (float*)(ws + alloc(256));
    float*  node_sum = (float*)(ws + alloc(256));
    size_t  zero_bytes = off_b;
    int*    offs     = (int*)(ws + alloc((size_t)N * 4));
    int*    pos      = (int*)(ws + alloc((size_t)E * 4));
    float*  esum_part= (float*)(ws + alloc((size_t)EDGE_BLOCKS * 64 * 4));
    __bf16* msgb  = (__bf16*)(ws + alloc((size_t)E * 64 * 2));
    __bf16* aggb  = (__bf16*)(ws + alloc((size_t)N * 64 * 2));
    __bf16* nfb   = (__bf16*)(ws + alloc((size_t)N * 64 * 2));
    __bf16* ub    = (__bf16*)(ws + alloc(256));
    __bf16* wt1e  = (__bf16*)(ws + alloc(128 * 256 * 2));
    __bf16* wt2e  = (__bf16*)(ws + alloc(64 * 128 * 2));
    __bf16* wt1n  = (__bf16*)(ws + alloc(128 * 192 * 2));
    __bf16* wt2n  = (__bf16*)(ws + alloc(64 * 128 * 2));

    float* out_n = (float*)d_out;
    float* out_e = out_n + (size_t)N * 64;
    float* out_u = out_e + (size_t)E * 64;

    hipMemsetAsync(d_ws, 0, zero_bytes, stream);
    prep_nf<<<(N * 64 / 4 + 255) / 256, 256, 0, stream>>>(nf, nfb, N * 64);
    prep_w<<<(73792 + 255) / 256, 256, 0, stream>>>(eW1, eW2, nW1, nW2, u,
                                                    wt1e, wt2e, wt1n, wt2n, ub);
    hist_kernel<<<(E + 255) / 256, 256, 0, stream>>>(dst, degi, E);
    scan_kernel<<<1, 1024, 0, stream>>>(degi, offs, N);
    fill_kernel<<<(E + 255) / 256, 256, 0, stream>>>(dst, offs, cursor, pos, E);
    edge_mfma<<<EDGE_BLOCKS, 256, 0, stream>>>(
        ef, nfb, ub, wt1e, wt2e, eb1, eb2, src, dst, pos, out_e, msgb, esum_part, E);
    reduce_cols<<<64, 256, 0, stream>>>(esum_part, edge_sum, EDGE_BLOCKS);
    agg_kernel<<<AGG_BLOCKS, 256, 0, stream>>>(
        msgb, offs, degi, aggb, N, AGG_BLOCKS * 4);
    node_mfma<<<(N + 63) / 64, 256, 0, stream>>>(
        nf, nfb, ub, aggb, wt1n, wt2n, nb1, nb2, out_n, node_sum, N);
    global_kernel<<<1, 128, 0, stream>>>(
        u, gW1, gb1, gW2, gb2, node_sum, edge_sum, out_u, N, E);
}

// Round 7
// 496.324 us; speedup vs baseline: 1.6543x; 1.6543x over previous
//
#include <hip/hip_runtime.h>
#include <hip/hip_bf16.h>

typedef __bf16 bf16x8 __attribute__((ext_vector_type(8)));
typedef __bf16 bf16x4 __attribute__((ext_vector_type(4)));
typedef float  f32x4  __attribute__((ext_vector_type(4)));
typedef unsigned short u16;

#define SWZ(row, byte) ((byte) ^ (((row) & 15) << 4))

__device__ __forceinline__ float bf16bits_to_f32(u16 v) {
    return __uint_as_float(((unsigned)v) << 16);
}

// ---------------------------------------------------------------------------
// prep: nf f32 -> bf16 (vectorized x4)
// ---------------------------------------------------------------------------
__global__ __launch_bounds__(256) void prep_nf(const float* __restrict__ nf,
                                               __bf16* __restrict__ nfb, int n) {
    int i = (blockIdx.x * 256 + threadIdx.x) * 4;
    if (i < n) {
        float4 v = *reinterpret_cast<const float4*>(nf + i);
        bf16x4 o;
        o[0] = (__bf16)v.x; o[1] = (__bf16)v.y; o[2] = (__bf16)v.z; o[3] = (__bf16)v.w;
        *reinterpret_cast<bf16x4*>(nfb + i) = o;
    }
}

// ---------------------------------------------------------------------------
// prep: weights -> bf16 in MFMA B-FRAGMENT ORDER.
// Fragment (kk, nt), lane l (lo=l&15, hi=l>>4), elem i:
//   value = W[k = kk*32 + hi*8 + i][n = nt*16 + lo]   (W row-major [K][N])
// flat index p = ((kk*NT + nt)*64 + l)*8 + i
// ---------------------------------------------------------------------------
__global__ __launch_bounds__(256) void prep_w(
    const float* __restrict__ eW1, const float* __restrict__ eW2,
    const float* __restrict__ nW1, const float* __restrict__ nW2,
    const float* __restrict__ u,
    __bf16* __restrict__ w1e_f, __bf16* __restrict__ w2e_f,
    __bf16* __restrict__ w1n_f, __bf16* __restrict__ w2n_f,
    __bf16* __restrict__ ub) {
    int p = blockIdx.x * 256 + threadIdx.x;
    if (p < 32768) {                       // eW1: K=256, N=128 -> 64 frags
        int i = p & 7, l = (p >> 3) & 63, f = p >> 9;
        int kk = f >> 3, nt = f & 7, lo = l & 15, hi = l >> 4;
        w1e_f[p] = (__bf16)eW1[(kk * 32 + hi * 8 + i) * 128 + nt * 16 + lo];
    } else if (p < 40960) {                // eW2: K=128, N=64 -> 16 frags
        int j = p - 32768;
        int i = j & 7, l = (j >> 3) & 63, g = j >> 9;
        int kk = g >> 2, nt = g & 3, lo = l & 15, hi = l >> 4;
        w2e_f[j] = (__bf16)eW2[(kk * 32 + hi * 8 + i) * 64 + nt * 16 + lo];
    } else if (p < 65536) {                // nW1: K=192, N=128 -> 48 frags
        int j = p - 40960;
        int i = j & 7, l = (j >> 3) & 63, f = j >> 9;
        int kk = f >> 3, nt = f & 7, lo = l & 15, hi = l >> 4;
        w1n_f[j] = (__bf16)nW1[(kk * 32 + hi * 8 + i) * 128 + nt * 16 + lo];
    } else if (p < 73728) {                // nW2: K=128, N=64 -> 16 frags
        int j = p - 65536;
        int i = j & 7, l = (j >> 3) & 63, g = j >> 9;
        int kk = g >> 2, nt = g & 3, lo = l & 15, hi = l >> 4;
        w2n_f[j] = (__bf16)nW2[(kk * 32 + hi * 8 + i) * 64 + nt * 16 + lo];
    } else if (p < 73792) {
        ub[p - 73728] = (__bf16)u[p - 73728];
    }
}

// ---------------------------------------------------------------------------
// CSR build: histogram of dst, exclusive scan, per-edge CSR position.
// ---------------------------------------------------------------------------
__global__ __launch_bounds__(256) void hist_kernel(const int* __restrict__ dst,
                                                   int* __restrict__ degi, int E) {
    int e = blockIdx.x * 256 + threadIdx.x;
    if (e < E) atomicAdd(&degi[dst[e]], 1);
}

__global__ __launch_bounds__(1024) void scan_kernel(const int* __restrict__ degi,
                                                    int* __restrict__ off, int N) {
    __shared__ int sm[1024];
    const int t = threadIdx.x;
    const int chunk = (N + 1023) / 1024;
    const int base = t * chunk;
    int local = 0;
    for (int i = 0; i < chunk; ++i) {
        int idx = base + i;
        if (idx < N) local += degi[idx];
    }
    sm[t] = local;
    __syncthreads();
    for (int d = 1; d < 1024; d <<= 1) {
        int v = sm[t];
        if (t >= d) v += sm[t - d];
        __syncthreads();
        sm[t] = v;
        __syncthreads();
    }
    int run = sm[t] - local;   // exclusive prefix of this chunk
    for (int i = 0; i < chunk; ++i) {
        int idx = base + i;
        if (idx < N) { off[idx] = run; run += degi[idx]; }
    }
}

__global__ __launch_bounds__(256) void fill_kernel(const int* __restrict__ dst,
                                                   const int* __restrict__ off,
                                                   int* __restrict__ cursor,
                                                   int* __restrict__ pos, int E) {
    int e = blockIdx.x * 256 + threadIdx.x;
    if (e < E) {
        int d = dst[e];
        int slot = atomicAdd(&cursor[d], 1);
        pos[e] = off[d] + slot;
    }
}

// ---------------------------------------------------------------------------
// Edge MLP, MFMA. 512 threads = 8 waves x 32 edges = 256 edges/block.
// Weights staged ONCE per block into LDS in fragment order (from w1f/w2f).
// All 16 A-gathers issued up-front; staging copy hides their latency.
// LDS map: [0,64K) W1 frags -> reused for h after barrier; [64K,80K) W2 frags.
// ---------------------------------------------------------------------------
__global__ __launch_bounds__(512) void edge_mfma(
    const float* __restrict__ ef,
    const __bf16* __restrict__ nfb, const __bf16* __restrict__ ub,
    const bf16x8* __restrict__ w1f, const bf16x8* __restrict__ w2f,
    const float* __restrict__ b1, const float* __restrict__ b2,
    const int* __restrict__ src, const int* __restrict__ dst,
    const int* __restrict__ pos,
    float* __restrict__ out_e, __bf16* __restrict__ msgb,
    float* __restrict__ esum_part,
    int E)
{
    extern __shared__ char lds[];
    const int tid = threadIdx.x;
    const int w = tid >> 6, l = tid & 63;
    const int lo = l & 15, hi = l >> 4;
    const long eb = (long)blockIdx.x * 256 + w * 32;

    int geA[2], srcA[2], dstA[2];
#pragma unroll
    for (int mt = 0; mt < 2; ++mt) {
        long ge = eb + mt * 16 + lo;
        geA[mt] = (ge < E) ? (int)ge : 0;
        srcA[mt] = src[geA[mt]];
        dstA[mt] = dst[geA[mt]];
    }

    // ---- issue ALL A-fragment gathers up-front (latency hidden by staging)
    bf16x8 afr[8][2];
#pragma unroll
    for (int kk = 0; kk < 8; ++kk) {
        const int koff = (kk & 1) * 32 + hi * 8;
        const int sec = kk >> 1;
#pragma unroll
        for (int mt = 0; mt < 2; ++mt) {
            if (sec == 0) {
                afr[kk][mt] = *(const bf16x8*)(nfb + (size_t)srcA[mt] * 64 + koff);
            } else if (sec == 1) {
                afr[kk][mt] = *(const bf16x8*)(nfb + (size_t)dstA[mt] * 64 + koff);
            } else if (sec == 2) {
                const float* p = ef + (size_t)geA[mt] * 64 + koff;
                float4 v0 = *(const float4*)p;
                float4 v1 = *(const float4*)(p + 4);
                bf16x8 t;
                t[0] = (__bf16)v0.x; t[1] = (__bf16)v0.y; t[2] = (__bf16)v0.z; t[3] = (__bf16)v0.w;
                t[4] = (__bf16)v1.x; t[5] = (__bf16)v1.y; t[6] = (__bf16)v1.z; t[7] = (__bf16)v1.w;
                afr[kk][mt] = t;
            } else {
                afr[kk][mt] = *(const bf16x8*)(ub + koff);
            }
        }
    }

    // ---- stage weights into LDS (linear, coalesced, conflict-free)
#pragma unroll
    for (int p = tid; p < 4096; p += 512)
        *(bf16x8*)(lds + p * 16) = w1f[p];
#pragma unroll
    for (int p = tid; p < 1024; p += 512)
        *(bf16x8*)(lds + 65536 + p * 16) = w2f[p];
    __syncthreads();

    float b1v[8];
#pragma unroll
    for (int nt = 0; nt < 8; ++nt) b1v[nt] = b1[nt * 16 + lo];
    float b2v[4];
#pragma unroll
    for (int nt = 0; nt < 4; ++nt) b2v[nt] = b2[nt * 16 + lo];

    // ---- layer 1: K=256, B-frags from LDS
    f32x4 acc1[2][8] = {};
#pragma unroll
    for (int kk = 0; kk < 8; ++kk) {
#pragma unroll
        for (int nt = 0; nt < 8; ++nt) {
            bf16x8 bfr = *(const bf16x8*)(lds + ((kk * 8 + nt) * 64 + l) * 16);
            acc1[0][nt] = __builtin_amdgcn_mfma_f32_16x16x32_bf16(afr[kk][0], bfr, acc1[0][nt], 0, 0, 0);
            acc1[1][nt] = __builtin_amdgcn_mfma_f32_16x16x32_bf16(afr[kk][1], bfr, acc1[1][nt], 0, 0, 0);
        }
    }
    __syncthreads();   // all W1 reads done; region reusable for h

    // ---- h = relu(acc1+b1) -> per-wave 8KB region (SWZ rows, conflict-free)
    char* hp = lds + w * 8192;
#pragma unroll
    for (int mt = 0; mt < 2; ++mt)
#pragma unroll
        for (int nt = 0; nt < 8; ++nt) {
            int col = nt * 16 + lo;
#pragma unroll
            for (int r = 0; r < 4; ++r) {
                int row = mt * 16 + hi * 4 + r;
                float hv = fmaxf(acc1[mt][nt][r] + b1v[nt], 0.0f);
                *(__bf16*)(hp + SWZ(row, row * 256 + col * 2)) = (__bf16)hv;
            }
        }

    // ---- layer 2: K=128, A from h (per-wave), B-frags from LDS [64K,80K)
    f32x4 acc2[2][4] = {};
#pragma unroll
    for (int kk = 0; kk < 4; ++kk) {
        int kb = (kk * 32 + hi * 8) * 2;
        bf16x8 a0 = *(const bf16x8*)(hp + SWZ(lo, lo * 256 + kb));
        bf16x8 a1 = *(const bf16x8*)(hp + SWZ(16 + lo, (16 + lo) * 256 + kb));
#pragma unroll
        for (int nt = 0; nt < 4; ++nt) {
            bf16x8 bfr = *(const bf16x8*)(lds + 65536 + ((kk * 4 + nt) * 64 + l) * 16);
            acc2[0][nt] = __builtin_amdgcn_mfma_f32_16x16x32_bf16(a0, bfr, acc2[0][nt], 0, 0, 0);
            acc2[1][nt] = __builtin_amdgcn_mfma_f32_16x16x32_bf16(a1, bfr, acc2[1][nt], 0, 0, 0);
        }
    }

    // ---- epilogue: residual store + CSR-ordered bf16 msg + wave esum partial
    float vsum[4] = {0.f, 0.f, 0.f, 0.f};
#pragma unroll
    for (int mt = 0; mt < 2; ++mt)
#pragma unroll
        for (int r = 0; r < 4; ++r) {
            long ge = eb + mt * 16 + hi * 4 + r;
            if (ge >= E) continue;
            int gei = (int)ge;
            size_t mb = (size_t)pos[gei] * 64;
#pragma unroll
            for (int nt = 0; nt < 4; ++nt) {
                int col = nt * 16 + lo;
                float msg = acc2[mt][nt][r] + b2v[nt];
                out_e[(size_t)gei * 64 + col] = msg + ef[(size_t)gei * 64 + col];
                msgb[mb + col] = (__bf16)msg;
                vsum[nt] += msg;
            }
        }
#pragma unroll
    for (int nt = 0; nt < 4; ++nt) {
        float v = vsum[nt];
        v += __shfl_xor(v, 16);
        v += __shfl_xor(v, 32);
        if (l < 16) esum_part[((size_t)blockIdx.x * 8 + w) * 64 + nt * 16 + l] = v;
    }
}

// ---------------------------------------------------------------------------
// Aggregate: wave per node; msgb rows are CSR-contiguous.
// ---------------------------------------------------------------------------
__global__ __launch_bounds__(256) void agg_kernel(
    const __bf16* __restrict__ msgb,
    const int* __restrict__ off, const int* __restrict__ degi,
    __bf16* __restrict__ aggb, int N, int n_waves)
{
    const int tid = threadIdx.x;
    const int l = tid & 63;
    const int q = l >> 4, lc = l & 15;
    const int gw = blockIdx.x * 4 + (tid >> 6);

    for (int n = gw; n < N; n += n_waves) {
        int j0 = off[n];
        int dg = degi[n];
        float s0 = 0.f, s1 = 0.f, s2 = 0.f, s3 = 0.f;
        for (int j = 0; j < dg; j += 4) {
            int row = j + q;
            if (row < dg) {
                ushort4 v = *(const ushort4*)(msgb + (size_t)(j0 + row) * 64 + lc * 4);
                s0 += bf16bits_to_f32(v.x);
                s1 += bf16bits_to_f32(v.y);
                s2 += bf16bits_to_f32(v.z);
                s3 += bf16bits_to_f32(v.w);
            }
        }
        s0 += __shfl_xor(s0, 16); s0 += __shfl_xor(s0, 32);
        s1 += __shfl_xor(s1, 16); s1 += __shfl_xor(s1, 32);
        s2 += __shfl_xor(s2, 16); s2 += __shfl_xor(s2, 32);
        s3 += __shfl_xor(s3, 16); s3 += __shfl_xor(s3, 32);
        if (l < 16) {
            float inv = 1.0f / fmaxf((float)dg, 1.0f);
            bf16x4 o;
            o[0] = (__bf16)(s0 * inv); o[1] = (__bf16)(s1 * inv);
            o[2] = (__bf16)(s2 * inv); o[3] = (__bf16)(s3 * inv);
            *(bf16x4*)(aggb + (size_t)n * 64 + lc * 4) = o;
        }
    }
}

// ---------------------------------------------------------------------------
// Node MLP, MFMA. Same structure as edge_mfma; K=192 (aggb | nfb | u).
// LDS: [0,48K) W1n frags (reused for h at [0,64K)); [64K,80K) W2n frags.
// ---------------------------------------------------------------------------
__global__ __launch_bounds__(512) void node_mfma(
    const float* __restrict__ nf,
    const __bf16* __restrict__ nfb, const __bf16* __restrict__ ub,
    const __bf16* __restrict__ aggb,
    const bf16x8* __restrict__ w1f, const bf16x8* __restrict__ w2f,
    const float* __restrict__ b1, const float* __restrict__ b2,
    float* __restrict__ out_n, float* __restrict__ nsum_part,
    int N)
{
    extern __shared__ char lds[];
    const int tid = threadIdx.x;
    const int w = tid >> 6, l = tid & 63;
    const int lo = l & 15, hi = l >> 4;
    const long nb = (long)blockIdx.x * 256 + w * 32;

    int gnA[2];
#pragma unroll
    for (int mt = 0; mt < 2; ++mt) {
        long gn = nb + mt * 16 + lo;
        gnA[mt] = (gn < N) ? (int)gn : 0;
    }

    bf16x8 afr[6][2];
#pragma unroll
    for (int kk = 0; kk < 6; ++kk) {
        const int koff = (kk & 1) * 32 + hi * 8;
        const int sec = kk >> 1;
#pragma unroll
        for (int mt = 0; mt < 2; ++mt) {
            if (sec == 0) {
                afr[kk][mt] = *(const bf16x8*)(aggb + (size_t)gnA[mt] * 64 + koff);
            } else if (sec == 1) {
                afr[kk][mt] = *(const bf16x8*)(nfb + (size_t)gnA[mt] * 64 + koff);
            } else {
                afr[kk][mt] = *(const bf16x8*)(ub + koff);
            }
        }
    }

#pragma unroll
    for (int p = tid; p < 3072; p += 512)
        *(bf16x8*)(lds + p * 16) = w1f[p];
#pragma unroll
    for (int p = tid; p < 1024; p += 512)
        *(bf16x8*)(lds + 65536 + p * 16) = w2f[p];
    __syncthreads();

    float b1v[8];
#pragma unroll
    for (int nt = 0; nt < 8; ++nt) b1v[nt] = b1[nt * 16 + lo];
    float b2v[4];
#pragma unroll
    for (int nt = 0; nt < 4; ++nt) b2v[nt] = b2[nt * 16 + lo];

    f32x4 acc1[2][8] = {};
#pragma unroll
    for (int kk = 0; kk < 6; ++kk) {
#pragma unroll
        for (int nt = 0; nt < 8; ++nt) {
            bf16x8 bfr = *(const bf16x8*)(lds + ((kk * 8 + nt) * 64 + l) * 16);
            acc1[0][nt] = __builtin_amdgcn_mfma_f32_16x16x32_bf16(afr[kk][0], bfr, acc1[0][nt], 0, 0, 0);
            acc1[1][nt] = __builtin_amdgcn_mfma_f32_16x16x32_bf16(afr[kk][1], bfr, acc1[1][nt], 0, 0, 0);
        }
    }
    __syncthreads();

    char* hp = lds + w * 8192;
#pragma unroll
    for (int mt = 0; mt < 2; ++mt)
#pragma unroll
        for (int nt = 0; nt < 8; ++nt) {
            int col = nt * 16 + lo;
#pragma unroll
            for (int r = 0; r < 4; ++r) {
                int row = mt * 16 + hi * 4 + r;
                float hv = fmaxf(acc1[mt][nt][r] + b1v[nt], 0.0f);
                *(__bf16*)(hp + SWZ(row, row * 256 + col * 2)) = (__bf16)hv;
            }
        }

    f32x4 acc2[2][4] = {};
#pragma unroll
    for (int kk = 0; kk < 4; ++kk) {
        int kb = (kk * 32 + hi * 8) * 2;
        bf16x8 a0 = *(const bf16x8*)(hp + SWZ(lo, lo * 256 + kb));
        bf16x8 a1 = *(const bf16x8*)(hp + SWZ(16 + lo, (16 + lo) * 256 + kb));
#pragma unroll
        for (int nt = 0; nt < 4; ++nt) {
            bf16x8 bfr = *(const bf16x8*)(lds + 65536 + ((kk * 4 + nt) * 64 + l) * 16);
            acc2[0][nt] = __builtin_amdgcn_mfma_f32_16x16x32_bf16(a0, bfr, acc2[0][nt], 0, 0, 0);
            acc2[1][nt] = __builtin_amdgcn_mfma_f32_16x16x32_bf16(a1, bfr, acc2[1][nt], 0, 0, 0);
        }
    }

    float vsum[4] = {0.f, 0.f, 0.f, 0.f};
#pragma unroll
    for (int mt = 0; mt < 2; ++mt)
#pragma unroll
        for (int r = 0; r < 4; ++r) {
            long gn = nb + mt * 16 + hi * 4 + r;
            if (gn >= N) continue;
            int gni = (int)gn;
#pragma unroll
            for (int nt = 0; nt < 4; ++nt) {
                int col = nt * 16 + lo;
                float msg = acc2[mt][nt][r] + b2v[nt];
                out_n[(size_t)gni * 64 + col] = msg + nf[(size_t)gni * 64 + col];
                vsum[nt] += msg;
            }
        }
#pragma unroll
    for (int nt = 0; nt < 4; ++nt) {
        float v = vsum[nt];
        v += __shfl_xor(v, 16);
        v += __shfl_xor(v, 32);
        if (l < 16) nsum_part[((size_t)blockIdx.x * 8 + w) * 64 + nt * 16 + l] = v;
    }
}

// ---------------------------------------------------------------------------
// col-sum reduce: out[c] += sum_r in[r][c]
// ---------------------------------------------------------------------------
__global__ __launch_bounds__(256) void reduce_cols(const float* __restrict__ in,
                                                   float* __restrict__ out, int R) {
    int col = threadIdx.x & 63;
    int rbase = blockIdx.x * 4 + (threadIdx.x >> 6);
    float s = 0.f;
    for (int r = rbase; r < R; r += gridDim.x * 4)
        s += in[(size_t)r * 64 + col];
    __shared__ float sm[256];
    sm[threadIdx.x] = s;
    __syncthreads();
    if (threadIdx.x < 64) {
        float v = sm[threadIdx.x] + sm[threadIdx.x + 64] + sm[threadIdx.x + 128] + sm[threadIdx.x + 192];
        atomicAdd(&out[threadIdx.x], v);
    }
}

// ---------------------------------------------------------------------------
// Global MLP: single block.
// ---------------------------------------------------------------------------
__global__ __launch_bounds__(128) void global_kernel(
    const float* __restrict__ u,
    const float* __restrict__ W1, const float* __restrict__ b1,
    const float* __restrict__ W2, const float* __restrict__ b2,
    const float* __restrict__ node_sum, const float* __restrict__ edge_sum,
    float* __restrict__ out_u, int N, int E)
{
    __shared__ float gm[192];
    __shared__ float h[128];
    int tid = threadIdx.x;
    if (tid < 64) {
        gm[tid]       = node_sum[tid] / (float)N;
        gm[64 + tid]  = edge_sum[tid] / (float)E;
        gm[128 + tid] = u[tid];
    }
    __syncthreads();
    float a = b1[tid];
    for (int k = 0; k < 192; ++k) a = fmaf(gm[k], W1[k * 128 + tid], a);
    h[tid] = fmaxf(a, 0.f);
    __syncthreads();
    if (tid < 64) {
        float o = b2[tid];
        for (int k = 0; k < 128; ++k) o = fmaf(h[k], W2[k * 64 + tid], o);
        out_u[tid] = o + u[tid];
    }
}

extern "C" void kernel_launch(void* const* d_in, const int* in_sizes, int n_in,
                              void* d_out, int out_size, void* d_ws, size_t ws_size,
                              hipStream_t stream) {
    const float* nf  = (const float*)d_in[0];
    const float* ef  = (const float*)d_in[1];
    const float* u   = (const float*)d_in[2];
    const float* eW1 = (const float*)d_in[3];
    const float* eb1 = (const float*)d_in[4];
    const float* eW2 = (const float*)d_in[5];
    const float* eb2 = (const float*)d_in[6];
    const float* nW1 = (const float*)d_in[7];
    const float* nb1 = (const float*)d_in[8];
    const float* nW2 = (const float*)d_in[9];
    const float* nb2 = (const float*)d_in[10];
    const float* gW1 = (const float*)d_in[11];
    const float* gb1 = (const float*)d_in[12];
    const float* gW2 = (const float*)d_in[13];
    const float* gb2 = (const float*)d_in[14];
    const int*   src = (const int*)d_in[15];
    const int*   dst = (const int*)d_in[16];

    const int N = in_sizes[0] / 64;
    const int E = in_sizes[1] / 64;
    const int EDGE_BLOCKS = (E + 255) / 256;
    const int NODE_BLOCKS = (N + 255) / 256;
    const int AGG_BLOCKS = 2048;

    char* ws = (char*)d_ws;
    size_t off_b = 0;
    auto alloc = [&](size_t bytes) { size_t c = off_b; off_b += (bytes + 255) & ~(size_t)255; return c; };

    // zeroed region first: degi | cursor | edge_sum | node_sum
    int*    degi     = (int*)(ws + alloc((size_t)N * 4));
    int*    cursor   = (int*)(ws + alloc((size_t)N * 4));
    float*  edge_sum = (float*)(ws + alloc(256));
    float*  node_sum = (float*)(ws + alloc(256));
    size_t  zero_bytes = off_b;
    int*    offs     = (int*)(ws + alloc((size_t)N * 4));
    int*    pos      = (int*)(ws + alloc((size_t)E * 4));
    float*  esum_part= (float*)(ws + alloc((size_t)EDGE_BLOCKS * 8 * 64 * 4));
    float*  nsum_part= (float*)(ws + alloc((size_t)NODE_BLOCKS * 8 * 64 * 4));
    __bf16* msgb  = (__bf16*)(ws + alloc((size_t)E * 64 * 2));
    __bf16* aggb  = (__bf16*)(ws + alloc((size_t)N * 64 * 2));
    __bf16* nfb   = (__bf16*)(ws + alloc((size_t)N * 64 * 2));
    __bf16* ub    = (__bf16*)(ws + alloc(256));
    __bf16* w1e_f = (__bf16*)(ws + alloc(32768 * 2));
    __bf16* w2e_f = (__bf16*)(ws + alloc(8192 * 2));
    __bf16* w1n_f = (__bf16*)(ws + alloc(24576 * 2));
    __bf16* w2n_f = (__bf16*)(ws + alloc(8192 * 2));

    float* out_n = (float*)d_out;
    float* out_e = out_n + (size_t)N * 64;
    float* out_u = out_e + (size_t)E * 64;

    hipMemsetAsync(d_ws, 0, zero_bytes, stream);
    prep_nf<<<(N * 64 / 4 + 255) / 256, 256, 0, stream>>>(nf, nfb, N * 64);
    prep_w<<<(73792 + 255) / 256, 256, 0, stream>>>(eW1, eW2, nW1, nW2, u,
                                                    w1e_f, w2e_f, w1n_f, w2n_f, ub);
    hist_kernel<<<(E + 255) / 256, 256, 0, stream>>>(dst, degi, E);
    scan_kernel<<<1, 1024, 0, stream>>>(degi, offs, N);
    fill_kernel<<<(E + 255) / 256, 256, 0, stream>>>(dst, offs, cursor, pos, E);
    edge_mfma<<<EDGE_BLOCKS, 512, 81920, stream>>>(
        ef, nfb, ub, (const bf16x8*)w1e_f, (const bf16x8*)w2e_f, eb1, eb2,
        src, dst, pos, out_e, msgb, esum_part, E);
    reduce_cols<<<64, 256, 0, stream>>>(esum_part, edge_sum, EDGE_BLOCKS * 8);
    agg_kernel<<<AGG_BLOCKS, 256, 0, stream>>>(
        msgb, offs, degi, aggb, N, AGG_BLOCKS * 4);
    node_mfma<<<NODE_BLOCKS, 512, 81920, stream>>>(
        nf, nfb, ub, aggb, (const bf16x8*)w1n_f, (const bf16x8*)w2n_f,
        nb1, nb2, out_n, nsum_part, N);
    reduce_cols<<<16, 256, 0, stream>>>(nsum_part, node_sum, NODE_BLOCKS * 8);
    global_kernel<<<1, 128, 0, stream>>>(
        u, gW1, gb1, gW2, gb2, node_sum, edge_sum, out_u, N, E);
}

// Round 8
// 442.678 us; speedup vs baseline: 1.8548x; 1.1212x over previous
//
#include <hip/hip_runtime.h>
#include <hip/hip_bf16.h>

typedef __bf16 bf16x8 __attribute__((ext_vector_type(8)));
typedef __bf16 bf16x4 __attribute__((ext_vector_type(4)));
typedef float  f32x4  __attribute__((ext_vector_type(4)));
typedef unsigned short u16;

#define SWZ(row, byte) ((byte) ^ (((row) & 15) << 4))

__device__ __forceinline__ float bf16bits_to_f32(u16 v) {
    return __uint_as_float(((unsigned)v) << 16);
}

// ---------------------------------------------------------------------------
// prep: nf f32 -> bf16 (vectorized x4)
// ---------------------------------------------------------------------------
__global__ __launch_bounds__(256) void prep_nf(const float* __restrict__ nf,
                                               __bf16* __restrict__ nfb, int n) {
    int i = (blockIdx.x * 256 + threadIdx.x) * 4;
    if (i < n) {
        float4 v = *reinterpret_cast<const float4*>(nf + i);
        bf16x4 o;
        o[0] = (__bf16)v.x; o[1] = (__bf16)v.y; o[2] = (__bf16)v.z; o[3] = (__bf16)v.w;
        *reinterpret_cast<bf16x4*>(nfb + i) = o;
    }
}

// ---------------------------------------------------------------------------
// prep: weights -> bf16 in MFMA B-FRAGMENT ORDER.
// Fragment (kk, nt), lane l (lo=l&15, hi=l>>4), elem i:
//   value = W[k = kk*32 + hi*8 + i][n = nt*16 + lo]   (W row-major [K][N])
// flat index p = ((kk*NT + nt)*64 + l)*8 + i
// ---------------------------------------------------------------------------
__global__ __launch_bounds__(256) void prep_w(
    const float* __restrict__ eW1, const float* __restrict__ eW2,
    const float* __restrict__ nW1, const float* __restrict__ nW2,
    const float* __restrict__ u,
    __bf16* __restrict__ w1e_f, __bf16* __restrict__ w2e_f,
    __bf16* __restrict__ w1n_f, __bf16* __restrict__ w2n_f,
    __bf16* __restrict__ ub) {
    int p = blockIdx.x * 256 + threadIdx.x;
    if (p < 32768) {                       // eW1: K=256, N=128 -> 64 frags
        int i = p & 7, l = (p >> 3) & 63, f = p >> 9;
        int kk = f >> 3, nt = f & 7, lo = l & 15, hi = l >> 4;
        w1e_f[p] = (__bf16)eW1[(kk * 32 + hi * 8 + i) * 128 + nt * 16 + lo];
    } else if (p < 40960) {                // eW2: K=128, N=64 -> 16 frags
        int j = p - 32768;
        int i = j & 7, l = (j >> 3) & 63, g = j >> 9;
        int kk = g >> 2, nt = g & 3, lo = l & 15, hi = l >> 4;
        w2e_f[j] = (__bf16)eW2[(kk * 32 + hi * 8 + i) * 64 + nt * 16 + lo];
    } else if (p < 65536) {                // nW1: K=192, N=128 -> 48 frags
        int j = p - 40960;
        int i = j & 7, l = (j >> 3) & 63, f = j >> 9;
        int kk = f >> 3, nt = f & 7, lo = l & 15, hi = l >> 4;
        w1n_f[j] = (__bf16)nW1[(kk * 32 + hi * 8 + i) * 128 + nt * 16 + lo];
    } else if (p < 73728) {                // nW2: K=128, N=64 -> 16 frags
        int j = p - 65536;
        int i = j & 7, l = (j >> 3) & 63, g = j >> 9;
        int kk = g >> 2, nt = g & 3, lo = l & 15, hi = l >> 4;
        w2n_f[j] = (__bf16)nW2[(kk * 32 + hi * 8 + i) * 64 + nt * 16 + lo];
    } else if (p < 73792) {
        ub[p - 73728] = (__bf16)u[p - 73728];
    }
}

// ---------------------------------------------------------------------------
// CSR build: histogram, 3-stage coalesced exclusive scan, per-edge position.
// ---------------------------------------------------------------------------
__global__ __launch_bounds__(256) void hist_kernel(const int* __restrict__ dst,
                                                   int* __restrict__ degi, int E) {
    int e = blockIdx.x * 256 + threadIdx.x;
    if (e < E) atomicAdd(&degi[dst[e]], 1);
}

// per-256-block local exclusive scan + block sums (coalesced)
__global__ __launch_bounds__(256) void scan_local(const int* __restrict__ degi,
                                                  int* __restrict__ offs,
                                                  int* __restrict__ bsum, int N) {
    __shared__ int sm[256];
    const int t = threadIdx.x;
    int i = blockIdx.x * 256 + t;
    int v = (i < N) ? degi[i] : 0;
    sm[t] = v;
    __syncthreads();
    for (int d = 1; d < 256; d <<= 1) {
        int a = (t >= d) ? sm[t - d] : 0;
        __syncthreads();
        sm[t] += a;
        __syncthreads();
    }
    if (i < N) offs[i] = sm[t] - v;             // exclusive
    if (t == 255) bsum[blockIdx.x] = sm[t];     // inclusive block total
}

// single block: exclusive scan of block sums (nb <= 256)
__global__ __launch_bounds__(256) void scan_blocks(const int* __restrict__ bsum,
                                                   int* __restrict__ bofs, int nb) {
    __shared__ int sm[256];
    const int t = threadIdx.x;
    int v = (t < nb) ? bsum[t] : 0;
    sm[t] = v;
    __syncthreads();
    for (int d = 1; d < 256; d <<= 1) {
        int a = (t >= d) ? sm[t - d] : 0;
        __syncthreads();
        sm[t] += a;
        __syncthreads();
    }
    if (t < nb) bofs[t] = sm[t] - v;
}

__global__ __launch_bounds__(256) void scan_add(int* __restrict__ offs,
                                                const int* __restrict__ bofs, int N) {
    int i = blockIdx.x * 256 + threadIdx.x;
    if (i < N) offs[i] += bofs[blockIdx.x];
}

__global__ __launch_bounds__(256) void fill_kernel(const int* __restrict__ dst,
                                                   const int* __restrict__ off,
                                                   int* __restrict__ cursor,
                                                   int* __restrict__ pos, int E) {
    int e = blockIdx.x * 256 + threadIdx.x;
    if (e < E) {
        int d = dst[e];
        int slot = atomicAdd(&cursor[d], 1);
        pos[e] = off[d] + slot;
    }
}

// ---------------------------------------------------------------------------
// Edge MLP, MFMA. 512 threads = 8 waves x 16 edges = 128 edges/block.
// LDS 48KB: [0,32K) = W1 half-buffer (two-phase stage) -> reused as h;
//           [32K,48K) = W2 frags.  2 blocks/CU target (16 waves).
// ---------------------------------------------------------------------------
__global__ __launch_bounds__(512, 4) void edge_mfma(
    const float* __restrict__ ef,
    const __bf16* __restrict__ nfb, const __bf16* __restrict__ ub,
    const bf16x8* __restrict__ w1f, const bf16x8* __restrict__ w2f,
    const float* __restrict__ b1, const float* __restrict__ b2,
    const int* __restrict__ src, const int* __restrict__ dst,
    const int* __restrict__ pos,
    float* __restrict__ out_e, __bf16* __restrict__ msgb,
    float* __restrict__ esum_part,
    int E)
{
    __shared__ alignas(16) char lds[49152];
    const int tid = threadIdx.x;
    const int w = tid >> 6, l = tid & 63;
    const int lo = l & 15, hi = l >> 4;
    const long eb = (long)blockIdx.x * 128 + w * 16;

    long geL = eb + lo;
    const int geA = (geL < E) ? (int)geL : 0;
    const int srcA = src[geA];
    const int dstA = dst[geA];

    // prefetch epilogue CSR positions (broadcast loads, latency hidden)
    int posA[4];
#pragma unroll
    for (int r = 0; r < 4; ++r) {
        long ge = eb + hi * 4 + r;
        posA[r] = pos[(ge < E) ? (int)ge : 0];
    }

    // ---- issue all A-fragment gathers up-front
    bf16x8 afr[8];
#pragma unroll
    for (int kk = 0; kk < 8; ++kk) {
        const int koff = (kk & 1) * 32 + hi * 8;
        const int sec = kk >> 1;
        if (sec == 0) {
            afr[kk] = *(const bf16x8*)(nfb + (size_t)srcA * 64 + koff);
        } else if (sec == 1) {
            afr[kk] = *(const bf16x8*)(nfb + (size_t)dstA * 64 + koff);
        } else if (sec == 2) {
            const float* p = ef + (size_t)geA * 64 + koff;
            float4 v0 = *(const float4*)p;
            float4 v1 = *(const float4*)(p + 4);
            bf16x8 t;
            t[0] = (__bf16)v0.x; t[1] = (__bf16)v0.y; t[2] = (__bf16)v0.z; t[3] = (__bf16)v0.w;
            t[4] = (__bf16)v1.x; t[5] = (__bf16)v1.y; t[6] = (__bf16)v1.z; t[7] = (__bf16)v1.w;
            afr[kk] = t;
        } else {
            afr[kk] = *(const bf16x8*)(ub + koff);
        }
    }

    float b1v[8];
#pragma unroll
    for (int nt = 0; nt < 8; ++nt) b1v[nt] = b1[nt * 16 + lo];
    float b2v[4];
#pragma unroll
    for (int nt = 0; nt < 4; ++nt) b2v[nt] = b2[nt * 16 + lo];

    // ---- stage W1 half0 (frags 0..31) + W2
#pragma unroll
    for (int p = tid; p < 2048; p += 512)
        *(bf16x8*)(lds + p * 16) = w1f[p];
#pragma unroll
    for (int p = tid; p < 1024; p += 512)
        *(bf16x8*)(lds + 32768 + p * 16) = w2f[p];
    __syncthreads();

    // ---- layer 1, kk = 0..3
    f32x4 acc1[8] = {};
#pragma unroll
    for (int kk = 0; kk < 4; ++kk)
#pragma unroll
        for (int nt = 0; nt < 8; ++nt) {
            bf16x8 bfr = *(const bf16x8*)(lds + ((kk * 8 + nt) * 64 + l) * 16);
            acc1[nt] = __builtin_amdgcn_mfma_f32_16x16x32_bf16(afr[kk], bfr, acc1[nt], 0, 0, 0);
        }
    __syncthreads();

    // ---- stage W1 half1 (frags 32..63) into same buffer
#pragma unroll
    for (int p = tid; p < 2048; p += 512)
        *(bf16x8*)(lds + p * 16) = w1f[2048 + p];
    __syncthreads();

    // ---- layer 1, kk = 4..7
#pragma unroll
    for (int kk = 4; kk < 8; ++kk)
#pragma unroll
        for (int nt = 0; nt < 8; ++nt) {
            bf16x8 bfr = *(const bf16x8*)(lds + (((kk - 4) * 8 + nt) * 64 + l) * 16);
            acc1[nt] = __builtin_amdgcn_mfma_f32_16x16x32_bf16(afr[kk], bfr, acc1[nt], 0, 0, 0);
        }
    __syncthreads();   // all W1 reads done; [0,32K) reusable for h

    // ---- h = relu(acc1+b1) -> per-wave 4KB region (within-wave only; LDS ops
    //      of one wave execute in order, no barrier needed)
    char* hp = lds + w * 4096;
#pragma unroll
    for (int nt = 0; nt < 8; ++nt) {
        int col = nt * 16 + lo;
#pragma unroll
        for (int r = 0; r < 4; ++r) {
            int row = hi * 4 + r;
            float hv = fmaxf(acc1[nt][r] + b1v[nt], 0.0f);
            *(__bf16*)(hp + SWZ(row, row * 256 + col * 2)) = (__bf16)hv;
        }
    }

    // ---- layer 2: K=128, A from h (per-wave), B-frags from [32K,48K)
    f32x4 acc2[4] = {};
#pragma unroll
    for (int kk = 0; kk < 4; ++kk) {
        int kb = (kk * 32 + hi * 8) * 2;
        bf16x8 a0 = *(const bf16x8*)(hp + SWZ(lo, lo * 256 + kb));
#pragma unroll
        for (int nt = 0; nt < 4; ++nt) {
            bf16x8 bfr = *(const bf16x8*)(lds + 32768 + ((kk * 4 + nt) * 64 + l) * 16);
            acc2[nt] = __builtin_amdgcn_mfma_f32_16x16x32_bf16(a0, bfr, acc2[nt], 0, 0, 0);
        }
    }

    // ---- epilogue: residual store + CSR-ordered bf16 msg + wave esum partial
    float vsum[4] = {0.f, 0.f, 0.f, 0.f};
#pragma unroll
    for (int r = 0; r < 4; ++r) {
        long ge = eb + hi * 4 + r;
        if (ge >= E) continue;
        int gei = (int)ge;
        size_t mb = (size_t)posA[r] * 64;
#pragma unroll
        for (int nt = 0; nt < 4; ++nt) {
            int col = nt * 16 + lo;
            float msg = acc2[nt][r] + b2v[nt];
            out_e[(size_t)gei * 64 + col] = msg + ef[(size_t)gei * 64 + col];
            msgb[mb + col] = (__bf16)msg;
            vsum[nt] += msg;
        }
    }
#pragma unroll
    for (int nt = 0; nt < 4; ++nt) {
        float v = vsum[nt];
        v += __shfl_xor(v, 16);
        v += __shfl_xor(v, 32);
        if (l < 16) esum_part[((size_t)blockIdx.x * 8 + w) * 64 + nt * 16 + l] = v;
    }
}

// ---------------------------------------------------------------------------
// Aggregate: wave per node; msgb rows are CSR-contiguous.
// ---------------------------------------------------------------------------
__global__ __launch_bounds__(256) void agg_kernel(
    const __bf16* __restrict__ msgb,
    const int* __restrict__ off, const int* __restrict__ degi,
    __bf16* __restrict__ aggb, int N, int n_waves)
{
    const int tid = threadIdx.x;
    const int l = tid & 63;
    const int q = l >> 4, lc = l & 15;
    const int gw = blockIdx.x * 4 + (tid >> 6);

    for (int n = gw; n < N; n += n_waves) {
        int j0 = off[n];
        int dg = degi[n];
        float s0 = 0.f, s1 = 0.f, s2 = 0.f, s3 = 0.f;
        for (int j = 0; j < dg; j += 4) {
            int row = j + q;
            if (row < dg) {
                ushort4 v = *(const ushort4*)(msgb + (size_t)(j0 + row) * 64 + lc * 4);
                s0 += bf16bits_to_f32(v.x);
                s1 += bf16bits_to_f32(v.y);
                s2 += bf16bits_to_f32(v.z);
                s3 += bf16bits_to_f32(v.w);
            }
        }
        s0 += __shfl_xor(s0, 16); s0 += __shfl_xor(s0, 32);
        s1 += __shfl_xor(s1, 16); s1 += __shfl_xor(s1, 32);
        s2 += __shfl_xor(s2, 16); s2 += __shfl_xor(s2, 32);
        s3 += __shfl_xor(s3, 16); s3 += __shfl_xor(s3, 32);
        if (l < 16) {
            float inv = 1.0f / fmaxf((float)dg, 1.0f);
            bf16x4 o;
            o[0] = (__bf16)(s0 * inv); o[1] = (__bf16)(s1 * inv);
            o[2] = (__bf16)(s2 * inv); o[3] = (__bf16)(s3 * inv);
            *(bf16x4*)(aggb + (size_t)n * 64 + lc * 4) = o;
        }
    }
}

// ---------------------------------------------------------------------------
// Node MLP, MFMA. Same structure as edge_mfma; K=192 (aggb | nfb | u).
// W1n = 48 frags: halves of 24 frags (24KB) in [0,32K); W2 at [32K,48K).
// ---------------------------------------------------------------------------
__global__ __launch_bounds__(512, 4) void node_mfma(
    const float* __restrict__ nf,
    const __bf16* __restrict__ nfb, const __bf16* __restrict__ ub,
    const __bf16* __restrict__ aggb,
    const bf16x8* __restrict__ w1f, const bf16x8* __restrict__ w2f,
    const float* __restrict__ b1, const float* __restrict__ b2,
    float* __restrict__ out_n, float* __restrict__ nsum_part,
    int N)
{
    __shared__ alignas(16) char lds[49152];
    const int tid = threadIdx.x;
    const int w = tid >> 6, l = tid & 63;
    const int lo = l & 15, hi = l >> 4;
    const long nb = (long)blockIdx.x * 128 + w * 16;

    long gnL = nb + lo;
    const int gnA = (gnL < N) ? (int)gnL : 0;

    bf16x8 afr[6];
#pragma unroll
    for (int kk = 0; kk < 6; ++kk) {
        const int koff = (kk & 1) * 32 + hi * 8;
        const int sec = kk >> 1;
        if (sec == 0)      afr[kk] = *(const bf16x8*)(aggb + (size_t)gnA * 64 + koff);
        else if (sec == 1) afr[kk] = *(const bf16x8*)(nfb + (size_t)gnA * 64 + koff);
        else               afr[kk] = *(const bf16x8*)(ub + koff);
    }

    float b1v[8];
#pragma unroll
    for (int nt = 0; nt < 8; ++nt) b1v[nt] = b1[nt * 16 + lo];
    float b2v[4];
#pragma unroll
    for (int nt = 0; nt < 4; ++nt) b2v[nt] = b2[nt * 16 + lo];

    // stage W1n half0 (frags 0..23) + W2
#pragma unroll
    for (int p = tid; p < 1536; p += 512)
        *(bf16x8*)(lds + p * 16) = w1f[p];
#pragma unroll
    for (int p = tid; p < 1024; p += 512)
        *(bf16x8*)(lds + 32768 + p * 16) = w2f[p];
    __syncthreads();

    f32x4 acc1[8] = {};
#pragma unroll
    for (int kk = 0; kk < 3; ++kk)
#pragma unroll
        for (int nt = 0; nt < 8; ++nt) {
            bf16x8 bfr = *(const bf16x8*)(lds + ((kk * 8 + nt) * 64 + l) * 16);
            acc1[nt] = __builtin_amdgcn_mfma_f32_16x16x32_bf16(afr[kk], bfr, acc1[nt], 0, 0, 0);
        }
    __syncthreads();

#pragma unroll
    for (int p = tid; p < 1536; p += 512)
        *(bf16x8*)(lds + p * 16) = w1f[1536 + p];
    __syncthreads();

#pragma unroll
    for (int kk = 3; kk < 6; ++kk)
#pragma unroll
        for (int nt = 0; nt < 8; ++nt) {
            bf16x8 bfr = *(const bf16x8*)(lds + (((kk - 3) * 8 + nt) * 64 + l) * 16);
            acc1[nt] = __builtin_amdgcn_mfma_f32_16x16x32_bf16(afr[kk], bfr, acc1[nt], 0, 0, 0);
        }
    __syncthreads();

    char* hp = lds + w * 4096;
#pragma unroll
    for (int nt = 0; nt < 8; ++nt) {
        int col = nt * 16 + lo;
#pragma unroll
        for (int r = 0; r < 4; ++r) {
            int row = hi * 4 + r;
            float hv = fmaxf(acc1[nt][r] + b1v[nt], 0.0f);
            *(__bf16*)(hp + SWZ(row, row * 256 + col * 2)) = (__bf16)hv;
        }
    }

    f32x4 acc2[4] = {};
#pragma unroll
    for (int kk = 0; kk < 4; ++kk) {
        int kb = (kk * 32 + hi * 8) * 2;
        bf16x8 a0 = *(const bf16x8*)(hp + SWZ(lo, lo * 256 + kb));
#pragma unroll
        for (int nt = 0; nt < 4; ++nt) {
            bf16x8 bfr = *(const bf16x8*)(lds + 32768 + ((kk * 4 + nt) * 64 + l) * 16);
            acc2[nt] = __builtin_amdgcn_mfma_f32_16x16x32_bf16(a0, bfr, acc2[nt], 0, 0, 0);
        }
    }

    float vsum[4] = {0.f, 0.f, 0.f, 0.f};
#pragma unroll
    for (int r = 0; r < 4; ++r) {
        long gn = nb + hi * 4 + r;
        if (gn >= N) continue;
        int gni = (int)gn;
#pragma unroll
        for (int nt = 0; nt < 4; ++nt) {
            int col = nt * 16 + lo;
            float msg = acc2[nt][r] + b2v[nt];
            out_n[(size_t)gni * 64 + col] = msg + nf[(size_t)gni * 64 + col];
            vsum[nt] += msg;
        }
    }
#pragma unroll
    for (int nt = 0; nt < 4; ++nt) {
        float v = vsum[nt];
        v += __shfl_xor(v, 16);
        v += __shfl_xor(v, 32);
        if (l < 16) nsum_part[((size_t)blockIdx.x * 8 + w) * 64 + nt * 16 + l] = v;
    }
}

// ---------------------------------------------------------------------------
// col-sum reduce: out[c] += sum_r in[r][c]
// ---------------------------------------------------------------------------
__global__ __launch_bounds__(256) void reduce_cols(const float* __restrict__ in,
                                                   float* __restrict__ out, int R) {
    int col = threadIdx.x & 63;
    int rbase = blockIdx.x * 4 + (threadIdx.x >> 6);
    float s = 0.f;
    for (int r = rbase; r < R; r += gridDim.x * 4)
        s += in[(size_t)r * 64 + col];
    __shared__ float sm[256];
    sm[threadIdx.x] = s;
    __syncthreads();
    if (threadIdx.x < 64) {
        float v = sm[threadIdx.x] + sm[threadIdx.x + 64] + sm[threadIdx.x + 128] + sm[threadIdx.x + 192];
        atomicAdd(&out[threadIdx.x], v);
    }
}

// ---------------------------------------------------------------------------
// Global MLP: single block.
// ---------------------------------------------------------------------------
__global__ __launch_bounds__(128) void global_kernel(
    const float* __restrict__ u,
    const float* __restrict__ W1, const float* __restrict__ b1,
    const float* __restrict__ W2, const float* __restrict__ b2,
    const float* __restrict__ node_sum, const float* __restrict__ edge_sum,
    float* __restrict__ out_u, int N, int E)
{
    __shared__ float gm[192];
    __shared__ float h[128];
    int tid = threadIdx.x;
    if (tid < 64) {
        gm[tid]       = node_sum[tid] / (float)N;
        gm[64 + tid]  = edge_sum[tid] / (float)E;
        gm[128 + tid] = u[tid];
    }
    __syncthreads();
    float a = b1[tid];
    for (int k = 0; k < 192; ++k) a = fmaf(gm[k], W1[k * 128 + tid], a);
    h[tid] = fmaxf(a, 0.f);
    __syncthreads();
    if (tid < 64) {
        float o = b2[tid];
        for (int k = 0; k < 128; ++k) o = fmaf(h[k], W2[k * 64 + tid], o);
        out_u[tid] = o + u[tid];
    }
}

extern "C" void kernel_launch(void* const* d_in, const int* in_sizes, int n_in,
                              void* d_out, int out_size, void* d_ws, size_t ws_size,
                              hipStream_t stream) {
    const float* nf  = (const float*)d_in[0];
    const float* ef  = (const float*)d_in[1];
    const float* u   = (const float*)d_in[2];
    const float* eW1 = (const float*)d_in[3];
    const float* eb1 = (const float*)d_in[4];
    const float* eW2 = (const float*)d_in[5];
    const float* eb2 = (const float*)d_in[6];
    const float* nW1 = (const float*)d_in[7];
    const float* nb1 = (const float*)d_in[8];
    const float* nW2 = (const float*)d_in[9];
    const float* nb2 = (const float*)d_in[10];
    const float* gW1 = (const float*)d_in[11];
    const float* gb1 = (const float*)d_in[12];
    const float* gW2 = (const float*)d_in[13];
    const float* gb2 = (const float*)d_in[14];
    const int*   src = (const int*)d_in[15];
    const int*   dst = (const int*)d_in[16];

    const int N = in_sizes[0] / 64;
    const int E = in_sizes[1] / 64;
    const int EDGE_BLOCKS = (E + 127) / 128;
    const int NODE_BLOCKS = (N + 127) / 128;
    const int SCAN_NB = (N + 255) / 256;       // <= 256 for N <= 65536
    const int AGG_BLOCKS = 2048;

    char* ws = (char*)d_ws;
    size_t off_b = 0;
    auto alloc = [&](size_t bytes) { size_t c = off_b; off_b += (bytes + 255) & ~(size_t)255; return c; };

    // zeroed region first: degi | cursor | edge_sum | node_sum
    int*    degi     = (int*)(ws + alloc((size_t)N * 4));
    int*    cursor   = (int*)(ws + alloc((size_t)N * 4));
    float*  edge_sum = (float*)(ws + alloc(256));
    float*  node_sum = (float*)(ws + alloc(256));
    size_t  zero_bytes = off_b;
    int*    offs     = (int*)(ws + alloc((size_t)N * 4));
    int*    bsum     = (int*)(ws + alloc((size_t)SCAN_NB * 4));
    int*    bofs     = (int*)(ws + alloc((size_t)SCAN_NB * 4));
    int*    pos      = (int*)(ws + alloc((size_t)E * 4));
    float*  esum_part= (float*)(ws + alloc((size_t)EDGE_BLOCKS * 8 * 64 * 4));
    float*  nsum_part= (float*)(ws + alloc((size_t)NODE_BLOCKS * 8 * 64 * 4));
    __bf16* msgb  = (__bf16*)(ws + alloc((size_t)E * 64 * 2));
    __bf16* aggb  = (__bf16*)(ws + alloc((size_t)N * 64 * 2));
    __bf16* nfb   = (__bf16*)(ws + alloc((size_t)N * 64 * 2));
    __bf16* ub    = (__bf16*)(ws + alloc(256));
    __bf16* w1e_f = (__bf16*)(ws + alloc(32768 * 2));
    __bf16* w2e_f = (__bf16*)(ws + alloc(8192 * 2));
    __bf16* w1n_f = (__bf16*)(ws + alloc(24576 * 2));
    __bf16* w2n_f = (__bf16*)(ws + alloc(8192 * 2));

    float* out_n = (float*)d_out;
    float* out_e = out_n + (size_t)N * 64;
    float* out_u = out_e + (size_t)E * 64;

    hipMemsetAsync(d_ws, 0, zero_bytes, stream);
    prep_nf<<<(N * 64 / 4 + 255) / 256, 256, 0, stream>>>(nf, nfb, N * 64);
    prep_w<<<(73792 + 255) / 256, 256, 0, stream>>>(eW1, eW2, nW1, nW2, u,
                                                    w1e_f, w2e_f, w1n_f, w2n_f, ub);
    hist_kernel<<<(E + 255) / 256, 256, 0, stream>>>(dst, degi, E);
    scan_local<<<SCAN_NB, 256, 0, stream>>>(degi, offs, bsum, N);
    scan_blocks<<<1, 256, 0, stream>>>(bsum, bofs, SCAN_NB);
    scan_add<<<SCAN_NB, 256, 0, stream>>>(offs, bofs, N);
    fill_kernel<<<(E + 255) / 256, 256, 0, stream>>>(dst, offs, cursor, pos, E);
    edge_mfma<<<EDGE_BLOCKS, 512, 0, stream>>>(
        ef, nfb, ub, (const bf16x8*)w1e_f, (const bf16x8*)w2e_f, eb1, eb2,
        src, dst, pos, out_e, msgb, esum_part, E);
    reduce_cols<<<64, 256, 0, stream>>>(esum_part, edge_sum, EDGE_BLOCKS * 8);
    agg_kernel<<<AGG_BLOCKS, 256, 0, stream>>>(
        msgb, offs, degi, aggb, N, AGG_BLOCKS * 4);
    node_mfma<<<NODE_BLOCKS, 512, 0, stream>>>(
        nf, nfb, ub, aggb, (const bf16x8*)w1n_f, (const bf16x8*)w2n_f,
        nb1, nb2, out_n, nsum_part, N);
    reduce_cols<<<16, 256, 0, stream>>>(nsum_part, node_sum, NODE_BLOCKS * 8);
    global_kernel<<<1, 128, 0, stream>>>(
        u, gW1, gb1, gW2, gb2, node_sum, edge_sum, out_u, N, E);
}

// Round 9
// 397.352 us; speedup vs baseline: 2.0664x; 1.1141x over previous
//
#include <hip/hip_runtime.h>
#include <hip/hip_bf16.h>

typedef __bf16 bf16x8 __attribute__((ext_vector_type(8)));
typedef __bf16 bf16x4 __attribute__((ext_vector_type(4)));
typedef float  f32x4  __attribute__((ext_vector_type(4)));

#define SWZ(row, byte) ((byte) ^ (((row) & 15) << 4))

// ---------------------------------------------------------------------------
// prep_all: fused  [0,B_NF): nf->bf16 | [B_NF,B_NF+B_W): weights->frag order
//                  [B_NF+B_W, ...): dst histogram
// Fragment (kk,nt), lane l (lo=l&15,hi=l>>4), elem i:
//   value = W[k=kk*32+hi*8+i][n=nt*16+lo],  flat p = ((kk*NT+nt)*64+l)*8+i
// ---------------------------------------------------------------------------
__global__ __launch_bounds__(256) void prep_all(
    const float* __restrict__ nf, __bf16* __restrict__ nfb, int nElem,
    const float* __restrict__ eW1, const float* __restrict__ eW2,
    const float* __restrict__ nW1, const float* __restrict__ nW2,
    const float* __restrict__ u,
    __bf16* __restrict__ w1e_f, __bf16* __restrict__ w2e_f,
    __bf16* __restrict__ w1n_f, __bf16* __restrict__ w2n_f,
    __bf16* __restrict__ ub,
    const int* __restrict__ dst, int* __restrict__ degi, int E,
    int B_NF, int B_W)
{
    int b = blockIdx.x;
    if (b < B_NF) {
        int i = (b * 256 + threadIdx.x) * 4;
        if (i < nElem) {
            float4 v = *reinterpret_cast<const float4*>(nf + i);
            bf16x4 o;
            o[0] = (__bf16)v.x; o[1] = (__bf16)v.y; o[2] = (__bf16)v.z; o[3] = (__bf16)v.w;
            *reinterpret_cast<bf16x4*>(nfb + i) = o;
        }
    } else if (b < B_NF + B_W) {
        int p = (b - B_NF) * 256 + threadIdx.x;
        if (p < 32768) {                       // eW1: K=256,N=128 -> 64 frags
            int i = p & 7, l = (p >> 3) & 63, f = p >> 9;
            int kk = f >> 3, nt = f & 7, lo = l & 15, hi = l >> 4;
            w1e_f[p] = (__bf16)eW1[(kk * 32 + hi * 8 + i) * 128 + nt * 16 + lo];
        } else if (p < 40960) {                // eW2: K=128,N=64 -> 16 frags
            int j = p - 32768;
            int i = j & 7, l = (j >> 3) & 63, g = j >> 9;
            int kk = g >> 2, nt = g & 3, lo = l & 15, hi = l >> 4;
            w2e_f[j] = (__bf16)eW2[(kk * 32 + hi * 8 + i) * 64 + nt * 16 + lo];
        } else if (p < 65536) {                // nW1: K=192,N=128 -> 48 frags
            int j = p - 40960;
            int i = j & 7, l = (j >> 3) & 63, f = j >> 9;
            int kk = f >> 3, nt = f & 7, lo = l & 15, hi = l >> 4;
            w1n_f[j] = (__bf16)nW1[(kk * 32 + hi * 8 + i) * 128 + nt * 16 + lo];
        } else if (p < 73728) {                // nW2: K=128,N=64 -> 16 frags
            int j = p - 65536;
            int i = j & 7, l = (j >> 3) & 63, g = j >> 9;
            int kk = g >> 2, nt = g & 3, lo = l & 15, hi = l >> 4;
            w2n_f[j] = (__bf16)nW2[(kk * 32 + hi * 8 + i) * 64 + nt * 16 + lo];
        } else if (p < 73792) {
            ub[p - 73728] = (__bf16)u[p - 73728];
        }
    } else {
        int e = (b - B_NF - B_W) * 256 + threadIdx.x;
        if (e < E) atomicAdd(&degi[dst[e]], 1);
    }
}

// ---------------------------------------------------------------------------
// CSR build: 3-stage coalesced exclusive scan + CSR edge-list fill.
// ---------------------------------------------------------------------------
__global__ __launch_bounds__(256) void scan_local(const int* __restrict__ degi,
                                                  int* __restrict__ offs,
                                                  int* __restrict__ bsum, int N) {
    __shared__ int sm[256];
    const int t = threadIdx.x;
    int i = blockIdx.x * 256 + t;
    int v = (i < N) ? degi[i] : 0;
    sm[t] = v;
    __syncthreads();
    for (int d = 1; d < 256; d <<= 1) {
        int a = (t >= d) ? sm[t - d] : 0;
        __syncthreads();
        sm[t] += a;
        __syncthreads();
    }
    if (i < N) offs[i] = sm[t] - v;
    if (t == 255) bsum[blockIdx.x] = sm[t];
}

__global__ __launch_bounds__(256) void scan_blocks(const int* __restrict__ bsum,
                                                   int* __restrict__ bofs, int nb) {
    __shared__ int sm[256];
    const int t = threadIdx.x;
    int v = (t < nb) ? bsum[t] : 0;
    sm[t] = v;
    __syncthreads();
    for (int d = 1; d < 256; d <<= 1) {
        int a = (t >= d) ? sm[t - d] : 0;
        __syncthreads();
        sm[t] += a;
        __syncthreads();
    }
    if (t < nb) bofs[t] = sm[t] - v;
}

__global__ __launch_bounds__(256) void scan_add(int* __restrict__ offs,
                                                const int* __restrict__ bofs, int N) {
    int i = blockIdx.x * 256 + threadIdx.x;
    if (i < N) offs[i] += bofs[blockIdx.x];
}

__global__ __launch_bounds__(256) void fill_kernel(const int* __restrict__ dst,
                                                   const int* __restrict__ off,
                                                   int* __restrict__ cursor,
                                                   int* __restrict__ eidx, int E) {
    int e = blockIdx.x * 256 + threadIdx.x;
    if (e < E) {
        int d = dst[e];
        int slot = atomicAdd(&cursor[d], 1);
        eidx[off[d] + slot] = e;
    }
}

// ---------------------------------------------------------------------------
// Edge MLP, MFMA, CSR-ordered + fused segmented aggregation.
// 512 threads = 8 waves x 16 CSR slots = 128 edges/block.
// LDS 48KB: [0,32K) W1 half-stage (reused as h); [32K,48K) W2 frags.
// Epilogue: residual scatter to out_e[eidx]; per-wave dst-segmented
// reduction -> few f32 atomics into agg[N][64] (pre-division sums).
// ---------------------------------------------------------------------------
__global__ __launch_bounds__(512, 4) void edge_mfma(
    const float* __restrict__ ef,
    const __bf16* __restrict__ nfb, const __bf16* __restrict__ ub,
    const bf16x8* __restrict__ w1f, const bf16x8* __restrict__ w2f,
    const float* __restrict__ b1, const float* __restrict__ b2,
    const int* __restrict__ src, const int* __restrict__ dst,
    const int* __restrict__ eidx,
    float* __restrict__ out_e, float* __restrict__ agg,
    int E)
{
    __shared__ alignas(16) char lds[49152];
    const int tid = threadIdx.x;
    const int w = tid >> 6, l = tid & 63;
    const int lo = l & 15, hi = l >> 4;
    const long wb = (long)blockIdx.x * 128 + w * 16;   // CSR slot base of wave

    long jL = wb + lo;
    const bool vL = (jL < E);
    const int eA = vL ? eidx[jL] : 0;
    const int srcA = src[eA];
    const int dstA = vL ? dst[eA] : -1;     // -1 isolates invalid rows

    // ---- issue all A-fragment gathers up-front
    bf16x8 afr[8];
#pragma unroll
    for (int kk = 0; kk < 8; ++kk) {
        const int koff = (kk & 1) * 32 + hi * 8;
        const int sec = kk >> 1;
        if (sec == 0) {
            afr[kk] = *(const bf16x8*)(nfb + (size_t)srcA * 64 + koff);
        } else if (sec == 1) {
            int dg = (dstA >= 0) ? dstA : 0;
            afr[kk] = *(const bf16x8*)(nfb + (size_t)dg * 64 + koff);
        } else if (sec == 2) {
            const float* p = ef + (size_t)eA * 64 + koff;
            float4 v0 = *(const float4*)p;
            float4 v1 = *(const float4*)(p + 4);
            bf16x8 t;
            t[0] = (__bf16)v0.x; t[1] = (__bf16)v0.y; t[2] = (__bf16)v0.z; t[3] = (__bf16)v0.w;
            t[4] = (__bf16)v1.x; t[5] = (__bf16)v1.y; t[6] = (__bf16)v1.z; t[7] = (__bf16)v1.w;
            afr[kk] = t;
        } else {
            afr[kk] = *(const bf16x8*)(ub + koff);
        }
    }

    float b1v[8];
#pragma unroll
    for (int nt = 0; nt < 8; ++nt) b1v[nt] = b1[nt * 16 + lo];
    float b2v[4];
#pragma unroll
    for (int nt = 0; nt < 4; ++nt) b2v[nt] = b2[nt * 16 + lo];

    // ---- stage W1 half0 + W2
#pragma unroll
    for (int p = tid; p < 2048; p += 512)
        *(bf16x8*)(lds + p * 16) = w1f[p];
#pragma unroll
    for (int p = tid; p < 1024; p += 512)
        *(bf16x8*)(lds + 32768 + p * 16) = w2f[p];
    __syncthreads();

    // ---- layer 1, kk = 0..3
    f32x4 acc1[8] = {};
#pragma unroll
    for (int kk = 0; kk < 4; ++kk)
#pragma unroll
        for (int nt = 0; nt < 8; ++nt) {
            bf16x8 bfr = *(const bf16x8*)(lds + ((kk * 8 + nt) * 64 + l) * 16);
            acc1[nt] = __builtin_amdgcn_mfma_f32_16x16x32_bf16(afr[kk], bfr, acc1[nt], 0, 0, 0);
        }
    __syncthreads();

    // ---- stage W1 half1
#pragma unroll
    for (int p = tid; p < 2048; p += 512)
        *(bf16x8*)(lds + p * 16) = w1f[2048 + p];
    __syncthreads();

    // ---- layer 1, kk = 4..7
#pragma unroll
    for (int kk = 4; kk < 8; ++kk)
#pragma unroll
        for (int nt = 0; nt < 8; ++nt) {
            bf16x8 bfr = *(const bf16x8*)(lds + (((kk - 4) * 8 + nt) * 64 + l) * 16);
            acc1[nt] = __builtin_amdgcn_mfma_f32_16x16x32_bf16(afr[kk], bfr, acc1[nt], 0, 0, 0);
        }
    __syncthreads();   // all W1 reads done; [0,32K) reusable for h

    // ---- h = relu(acc1+b1) -> per-wave 4KB region
    char* hp = lds + w * 4096;
#pragma unroll
    for (int nt = 0; nt < 8; ++nt) {
        int col = nt * 16 + lo;
#pragma unroll
        for (int r = 0; r < 4; ++r) {
            int row = hi * 4 + r;
            float hv = fmaxf(acc1[nt][r] + b1v[nt], 0.0f);
            *(__bf16*)(hp + SWZ(row, row * 256 + col * 2)) = (__bf16)hv;
        }
    }

    // ---- layer 2
    f32x4 acc2[4] = {};
#pragma unroll
    for (int kk = 0; kk < 4; ++kk) {
        int kb = (kk * 32 + hi * 8) * 2;
        bf16x8 a0 = *(const bf16x8*)(hp + SWZ(lo, lo * 256 + kb));
#pragma unroll
        for (int nt = 0; nt < 4; ++nt) {
            bf16x8 bfr = *(const bf16x8*)(lds + 32768 + ((kk * 4 + nt) * 64 + l) * 16);
            acc2[nt] = __builtin_amdgcn_mfma_f32_16x16x32_bf16(a0, bfr, acc2[nt], 0, 0, 0);
        }
    }

    // ---- epilogue A: residual scatter to out_e[eidx]
#pragma unroll
    for (int r = 0; r < 4; ++r) {
        int row = hi * 4 + r;
        if (wb + row >= E) continue;
        int er = __shfl(eA, row);
#pragma unroll
        for (int nt = 0; nt < 4; ++nt) {
            int col = nt * 16 + lo;
            float msg = acc2[nt][r] + b2v[nt];
            out_e[(size_t)er * 64 + col] = msg + ef[(size_t)er * 64 + col];
        }
    }

    // ---- epilogue B: dst-segmented reduction -> f32 atomics into agg
    int dn = __shfl(dstA, (l + 1) & 63);
    unsigned long long bal = __ballot(dstA != dn);
    unsigned mm = ((unsigned)bal & 0x7FFFu) | 0x8000u;   // row15 always ends a segment
    int startRow = 0;
    while (mm) {
        int endRow = __ffs(mm);              // segment rows [startRow, endRow)
        int d = __shfl(dstA, startRow);      // uniform
        if (d >= 0) {
            float s0 = 0.f, s1 = 0.f, s2 = 0.f, s3 = 0.f;
#pragma unroll
            for (int r = 0; r < 4; ++r) {
                int row = hi * 4 + r;
                if (row >= startRow && row < endRow) {
                    s0 += acc2[0][r] + b2v[0];
                    s1 += acc2[1][r] + b2v[1];
                    s2 += acc2[2][r] + b2v[2];
                    s3 += acc2[3][r] + b2v[3];
                }
            }
            s0 += __shfl_xor(s0, 16); s0 += __shfl_xor(s0, 32);
            s1 += __shfl_xor(s1, 16); s1 += __shfl_xor(s1, 32);
            s2 += __shfl_xor(s2, 16); s2 += __shfl_xor(s2, 32);
            s3 += __shfl_xor(s3, 16); s3 += __shfl_xor(s3, 32);
            if (l < 16) {
                float* ap = agg + (size_t)d * 64;
                atomicAdd(ap + l,      s0);
                atomicAdd(ap + 16 + l, s1);
                atomicAdd(ap + 32 + l, s2);
                atomicAdd(ap + 48 + l, s3);
            }
        }
        startRow = endRow;
        mm &= mm - 1;
    }
}

// ---------------------------------------------------------------------------
// Node MLP, MFMA. K=192 (agg/deg | nfb | u); agg is f32 pre-division sums.
// ---------------------------------------------------------------------------
__global__ __launch_bounds__(512, 4) void node_mfma(
    const float* __restrict__ nf,
    const __bf16* __restrict__ nfb, const __bf16* __restrict__ ub,
    const float* __restrict__ agg, const int* __restrict__ degi,
    const bf16x8* __restrict__ w1f, const bf16x8* __restrict__ w2f,
    const float* __restrict__ b1, const float* __restrict__ b2,
    float* __restrict__ out_n, float* __restrict__ nsum_part,
    int N)
{
    __shared__ alignas(16) char lds[49152];
    const int tid = threadIdx.x;
    const int w = tid >> 6, l = tid & 63;
    const int lo = l & 15, hi = l >> 4;
    const long nb = (long)blockIdx.x * 128 + w * 16;

    long gnL = nb + lo;
    const int gnA = (gnL < N) ? (int)gnL : 0;
    const float inv = 1.0f / fmaxf((float)degi[gnA], 1.0f);

    bf16x8 afr[6];
#pragma unroll
    for (int kk = 0; kk < 6; ++kk) {
        const int koff = (kk & 1) * 32 + hi * 8;
        const int sec = kk >> 1;
        if (sec == 0) {
            const float* p = agg + (size_t)gnA * 64 + koff;
            float4 v0 = *(const float4*)p;
            float4 v1 = *(const float4*)(p + 4);
            bf16x8 t;
            t[0] = (__bf16)(v0.x * inv); t[1] = (__bf16)(v0.y * inv);
            t[2] = (__bf16)(v0.z * inv); t[3] = (__bf16)(v0.w * inv);
            t[4] = (__bf16)(v1.x * inv); t[5] = (__bf16)(v1.y * inv);
            t[6] = (__bf16)(v1.z * inv); t[7] = (__bf16)(v1.w * inv);
            afr[kk] = t;
        } else if (sec == 1) {
            afr[kk] = *(const bf16x8*)(nfb + (size_t)gnA * 64 + koff);
        } else {
            afr[kk] = *(const bf16x8*)(ub + koff);
        }
    }

    float b1v[8];
#pragma unroll
    for (int nt = 0; nt < 8; ++nt) b1v[nt] = b1[nt * 16 + lo];
    float b2v[4];
#pragma unroll
    for (int nt = 0; nt < 4; ++nt) b2v[nt] = b2[nt * 16 + lo];

    // stage W1n half0 (24 frags) + W2
#pragma unroll
    for (int p = tid; p < 1536; p += 512)
        *(bf16x8*)(lds + p * 16) = w1f[p];
#pragma unroll
    for (int p = tid; p < 1024; p += 512)
        *(bf16x8*)(lds + 32768 + p * 16) = w2f[p];
    __syncthreads();

    f32x4 acc1[8] = {};
#pragma unroll
    for (int kk = 0; kk < 3; ++kk)
#pragma unroll
        for (int nt = 0; nt < 8; ++nt) {
            bf16x8 bfr = *(const bf16x8*)(lds + ((kk * 8 + nt) * 64 + l) * 16);
            acc1[nt] = __builtin_amdgcn_mfma_f32_16x16x32_bf16(afr[kk], bfr, acc1[nt], 0, 0, 0);
        }
    __syncthreads();

#pragma unroll
    for (int p = tid; p < 1536; p += 512)
        *(bf16x8*)(lds + p * 16) = w1f[1536 + p];
    __syncthreads();

#pragma unroll
    for (int kk = 3; kk < 6; ++kk)
#pragma unroll
        for (int nt = 0; nt < 8; ++nt) {
            bf16x8 bfr = *(const bf16x8*)(lds + (((kk - 3) * 8 + nt) * 64 + l) * 16);
            acc1[nt] = __builtin_amdgcn_mfma_f32_16x16x32_bf16(afr[kk], bfr, acc1[nt], 0, 0, 0);
        }
    __syncthreads();

    char* hp = lds + w * 4096;
#pragma unroll
    for (int nt = 0; nt < 8; ++nt) {
        int col = nt * 16 + lo;
#pragma unroll
        for (int r = 0; r < 4; ++r) {
            int row = hi * 4 + r;
            float hv = fmaxf(acc1[nt][r] + b1v[nt], 0.0f);
            *(__bf16*)(hp + SWZ(row, row * 256 + col * 2)) = (__bf16)hv;
        }
    }

    f32x4 acc2[4] = {};
#pragma unroll
    for (int kk = 0; kk < 4; ++kk) {
        int kb = (kk * 32 + hi * 8) * 2;
        bf16x8 a0 = *(const bf16x8*)(hp + SWZ(lo, lo * 256 + kb));
#pragma unroll
        for (int nt = 0; nt < 4; ++nt) {
            bf16x8 bfr = *(const bf16x8*)(lds + 32768 + ((kk * 4 + nt) * 64 + l) * 16);
            acc2[nt] = __builtin_amdgcn_mfma_f32_16x16x32_bf16(a0, bfr, acc2[nt], 0, 0, 0);
        }
    }

    float vsum[4] = {0.f, 0.f, 0.f, 0.f};
#pragma unroll
    for (int r = 0; r < 4; ++r) {
        long gn = nb + hi * 4 + r;
        if (gn >= N) continue;
        int gni = (int)gn;
#pragma unroll
        for (int nt = 0; nt < 4; ++nt) {
            int col = nt * 16 + lo;
            float msg = acc2[nt][r] + b2v[nt];
            out_n[(size_t)gni * 64 + col] = msg + nf[(size_t)gni * 64 + col];
            vsum[nt] += msg;
        }
    }
#pragma unroll
    for (int nt = 0; nt < 4; ++nt) {
        float v = vsum[nt];
        v += __shfl_xor(v, 16);
        v += __shfl_xor(v, 32);
        if (l < 16) nsum_part[((size_t)blockIdx.x * 8 + w) * 64 + nt * 16 + l] = v;
    }
}

// ---------------------------------------------------------------------------
// col-sum reduce: out[c] += sum_r in[r][c]
// ---------------------------------------------------------------------------
__global__ __launch_bounds__(256) void reduce_cols(const float* __restrict__ in,
                                                   float* __restrict__ out, int R) {
    int col = threadIdx.x & 63;
    int rbase = blockIdx.x * 4 + (threadIdx.x >> 6);
    float s = 0.f;
    for (int r = rbase; r < R; r += gridDim.x * 4)
        s += in[(size_t)r * 64 + col];
    __shared__ float sm[256];
    sm[threadIdx.x] = s;
    __syncthreads();
    if (threadIdx.x < 64) {
        float v = sm[threadIdx.x] + sm[threadIdx.x + 64] + sm[threadIdx.x + 128] + sm[threadIdx.x + 192];
        atomicAdd(&out[threadIdx.x], v);
    }
}

// ---------------------------------------------------------------------------
// Global MLP: single block.
// ---------------------------------------------------------------------------
__global__ __launch_bounds__(128) void global_kernel(
    const float* __restrict__ u,
    const float* __restrict__ W1, const float* __restrict__ b1,
    const float* __restrict__ W2, const float* __restrict__ b2,
    const float* __restrict__ node_sum, const float* __restrict__ edge_sum,
    float* __restrict__ out_u, int N, int E)
{
    __shared__ float gm[192];
    __shared__ float h[128];
    int tid = threadIdx.x;
    if (tid < 64) {
        gm[tid]       = node_sum[tid] / (float)N;
        gm[64 + tid]  = edge_sum[tid] / (float)E;
        gm[128 + tid] = u[tid];
    }
    __syncthreads();
    float a = b1[tid];
    for (int k = 0; k < 192; ++k) a = fmaf(gm[k], W1[k * 128 + tid], a);
    h[tid] = fmaxf(a, 0.f);
    __syncthreads();
    if (tid < 64) {
        float o = b2[tid];
        for (int k = 0; k < 128; ++k) o = fmaf(h[k], W2[k * 64 + tid], o);
        out_u[tid] = o + u[tid];
    }
}

extern "C" void kernel_launch(void* const* d_in, const int* in_sizes, int n_in,
                              void* d_out, int out_size, void* d_ws, size_t ws_size,
                              hipStream_t stream) {
    const float* nf  = (const float*)d_in[0];
    const float* ef  = (const float*)d_in[1];
    const float* u   = (const float*)d_in[2];
    const float* eW1 = (const float*)d_in[3];
    const float* eb1 = (const float*)d_in[4];
    const float* eW2 = (const float*)d_in[5];
    const float* eb2 = (const float*)d_in[6];
    const float* nW1 = (const float*)d_in[7];
    const float* nb1 = (const float*)d_in[8];
    const float* nW2 = (const float*)d_in[9];
    const float* nb2 = (const float*)d_in[10];
    const float* gW1 = (const float*)d_in[11];
    const float* gb1 = (const float*)d_in[12];
    const float* gW2 = (const float*)d_in[13];
    const float* gb2 = (const float*)d_in[14];
    const int*   src = (const int*)d_in[15];
    const int*   dst = (const int*)d_in[16];

    const int N = in_sizes[0] / 64;
    const int E = in_sizes[1] / 64;
    const int EDGE_BLOCKS = (E + 127) / 128;
    const int NODE_BLOCKS = (N + 127) / 128;
    const int SCAN_NB = (N + 255) / 256;       // <= 256 for N <= 65536

    char* ws = (char*)d_ws;
    size_t off_b = 0;
    auto alloc = [&](size_t bytes) { size_t c = off_b; off_b += (bytes + 255) & ~(size_t)255; return c; };

    // zeroed region first: degi | cursor | edge_sum | node_sum | agg
    int*    degi     = (int*)(ws + alloc((size_t)N * 4));
    int*    cursor   = (int*)(ws + alloc((size_t)N * 4));
    float*  edge_sum = (float*)(ws + alloc(256));
    float*  node_sum = (float*)(ws + alloc(256));
    float*  agg      = (float*)(ws + alloc((size_t)N * 64 * 4));
    size_t  zero_bytes = off_b;
    int*    offs     = (int*)(ws + alloc((size_t)N * 4));
    int*    bsum     = (int*)(ws + alloc((size_t)SCAN_NB * 4));
    int*    bofs     = (int*)(ws + alloc((size_t)SCAN_NB * 4));
    int*    eidx     = (int*)(ws + alloc((size_t)E * 4));
    float*  nsum_part= (float*)(ws + alloc((size_t)NODE_BLOCKS * 8 * 64 * 4));
    __bf16* nfb   = (__bf16*)(ws + alloc((size_t)N * 64 * 2));
    __bf16* ub    = (__bf16*)(ws + alloc(256));
    __bf16* w1e_f = (__bf16*)(ws + alloc(32768 * 2));
    __bf16* w2e_f = (__bf16*)(ws + alloc(8192 * 2));
    __bf16* w1n_f = (__bf16*)(ws + alloc(24576 * 2));
    __bf16* w2n_f = (__bf16*)(ws + alloc(8192 * 2));

    float* out_n = (float*)d_out;
    float* out_e = out_n + (size_t)N * 64;
    float* out_u = out_e + (size_t)E * 64;

    const int B_NF = (N * 16 + 255) / 256;     // N*64/4 threads
    const int B_W  = (73792 + 255) / 256;
    const int B_H  = (E + 255) / 256;

    hipMemsetAsync(d_ws, 0, zero_bytes, stream);
    prep_all<<<B_NF + B_W + B_H, 256, 0, stream>>>(
        nf, nfb, N * 64, eW1, eW2, nW1, nW2, u,
        w1e_f, w2e_f, w1n_f, w2n_f, ub, dst, degi, E, B_NF, B_W);
    scan_local<<<SCAN_NB, 256, 0, stream>>>(degi, offs, bsum, N);
    scan_blocks<<<1, 256, 0, stream>>>(bsum, bofs, SCAN_NB);
    scan_add<<<SCAN_NB, 256, 0, stream>>>(offs, bofs, N);
    fill_kernel<<<(E + 255) / 256, 256, 0, stream>>>(dst, offs, cursor, eidx, E);
    edge_mfma<<<EDGE_BLOCKS, 512, 0, stream>>>(
        ef, nfb, ub, (const bf16x8*)w1e_f, (const bf16x8*)w2e_f, eb1, eb2,
        src, dst, eidx, out_e, agg, E);
    reduce_cols<<<128, 256, 0, stream>>>(agg, edge_sum, N);
    node_mfma<<<NODE_BLOCKS, 512, 0, stream>>>(
        nf, nfb, ub, agg, degi, (const bf16x8*)w1n_f, (const bf16x8*)w2n_f,
        nb1, nb2, out_n, nsum_part, N);
    reduce_cols<<<16, 256, 0, stream>>>(nsum_part, node_sum, NODE_BLOCKS * 8);
    global_kernel<<<1, 128, 0, stream>>>(
        u, gW1, gb1, gW2, gb2, node_sum, edge_sum, out_u, N, E);
}

// Round 10
// 366.832 us; speedup vs baseline: 2.2383x; 1.0832x over previous
//
#include <hip/hip_runtime.h>
#include <hip/hip_bf16.h>

typedef __bf16 bf16x8 __attribute__((ext_vector_type(8)));
typedef __bf16 bf16x4 __attribute__((ext_vector_type(4)));
typedef float  f32x4  __attribute__((ext_vector_type(4)));

#define SWZ(row, byte) ((byte) ^ (((row) & 15) << 4))

// ---------------------------------------------------------------------------
// prep_all: fused  [0,B_NF): nf->bf16 | [B_NF,B_NF+B_W): weights->frag order
//                  [B_NF+B_W, ...): dst histogram
// ---------------------------------------------------------------------------
__global__ __launch_bounds__(256) void prep_all(
    const float* __restrict__ nf, __bf16* __restrict__ nfb, int nElem,
    const float* __restrict__ eW1, const float* __restrict__ eW2,
    const float* __restrict__ nW1, const float* __restrict__ nW2,
    const float* __restrict__ u,
    __bf16* __restrict__ w1e_f, __bf16* __restrict__ w2e_f,
    __bf16* __restrict__ w1n_f, __bf16* __restrict__ w2n_f,
    __bf16* __restrict__ ub,
    const int* __restrict__ dst, int* __restrict__ degi, int E,
    int B_NF, int B_W)
{
    int b = blockIdx.x;
    if (b < B_NF) {
        int i = (b * 256 + threadIdx.x) * 4;
        if (i < nElem) {
            float4 v = *reinterpret_cast<const float4*>(nf + i);
            bf16x4 o;
            o[0] = (__bf16)v.x; o[1] = (__bf16)v.y; o[2] = (__bf16)v.z; o[3] = (__bf16)v.w;
            *reinterpret_cast<bf16x4*>(nfb + i) = o;
        }
    } else if (b < B_NF + B_W) {
        int p = (b - B_NF) * 256 + threadIdx.x;
        if (p < 32768) {                       // eW1: K=256,N=128 -> 64 frags
            int i = p & 7, l = (p >> 3) & 63, f = p >> 9;
            int kk = f >> 3, nt = f & 7, lo = l & 15, hi = l >> 4;
            w1e_f[p] = (__bf16)eW1[(kk * 32 + hi * 8 + i) * 128 + nt * 16 + lo];
        } else if (p < 40960) {                // eW2: K=128,N=64 -> 16 frags
            int j = p - 32768;
            int i = j & 7, l = (j >> 3) & 63, g = j >> 9;
            int kk = g >> 2, nt = g & 3, lo = l & 15, hi = l >> 4;
            w2e_f[j] = (__bf16)eW2[(kk * 32 + hi * 8 + i) * 64 + nt * 16 + lo];
        } else if (p < 65536) {                // nW1: K=192,N=128 -> 48 frags
            int j = p - 40960;
            int i = j & 7, l = (j >> 3) & 63, f = j >> 9;
            int kk = f >> 3, nt = f & 7, lo = l & 15, hi = l >> 4;
            w1n_f[j] = (__bf16)nW1[(kk * 32 + hi * 8 + i) * 128 + nt * 16 + lo];
        } else if (p < 73728) {                // nW2: K=128,N=64 -> 16 frags
            int j = p - 65536;
            int i = j & 7, l = (j >> 3) & 63, g = j >> 9;
            int kk = g >> 2, nt = g & 3, lo = l & 15, hi = l >> 4;
            w2n_f[j] = (__bf16)nW2[(kk * 32 + hi * 8 + i) * 64 + nt * 16 + lo];
        } else if (p < 73792) {
            ub[p - 73728] = (__bf16)u[p - 73728];
        }
    } else {
        int e = (b - B_NF - B_W) * 256 + threadIdx.x;
        if (e < E) atomicAdd(&degi[dst[e]], 1);
    }
}

// ---------------------------------------------------------------------------
// CSR build: 3-stage coalesced exclusive scan + CSR edge-list fill.
// ---------------------------------------------------------------------------
__global__ __launch_bounds__(256) void scan_local(const int* __restrict__ degi,
                                                  int* __restrict__ offs,
                                                  int* __restrict__ bsum, int N) {
    __shared__ int sm[256];
    const int t = threadIdx.x;
    int i = blockIdx.x * 256 + t;
    int v = (i < N) ? degi[i] : 0;
    sm[t] = v;
    __syncthreads();
    for (int d = 1; d < 256; d <<= 1) {
        int a = (t >= d) ? sm[t - d] : 0;
        __syncthreads();
        sm[t] += a;
        __syncthreads();
    }
    if (i < N) offs[i] = sm[t] - v;
    if (t == 255) bsum[blockIdx.x] = sm[t];
}

__global__ __launch_bounds__(256) void scan_blocks(const int* __restrict__ bsum,
                                                   int* __restrict__ bofs, int nb) {
    __shared__ int sm[256];
    const int t = threadIdx.x;
    int v = (t < nb) ? bsum[t] : 0;
    sm[t] = v;
    __syncthreads();
    for (int d = 1; d < 256; d <<= 1) {
        int a = (t >= d) ? sm[t - d] : 0;
        __syncthreads();
        sm[t] += a;
        __syncthreads();
    }
    if (t < nb) bofs[t] = sm[t] - v;
}

__global__ __launch_bounds__(256) void scan_add(int* __restrict__ offs,
                                                const int* __restrict__ bofs, int N) {
    int i = blockIdx.x * 256 + threadIdx.x;
    if (i < N) offs[i] += bofs[blockIdx.x];
}

__global__ __launch_bounds__(256) void fill_kernel(const int* __restrict__ dst,
                                                   const int* __restrict__ off,
                                                   int* __restrict__ cursor,
                                                   int* __restrict__ eidx, int E) {
    int e = blockIdx.x * 256 + threadIdx.x;
    if (e < E) {
        int d = dst[e];
        int slot = atomicAdd(&cursor[d], 1);
        eidx[off[d] + slot] = e;
    }
}

// ---------------------------------------------------------------------------
// Edge MLP, MFMA, CSR-ordered + fused segmented aggregation.
// 512 threads = 8 waves x 16 CSR slots = 128 edges/block.
// LDS 48KB: [0,32K) W1 half-stage (reused as h); [32K,48K) W2 frags.
// Residual ef values preloaded during the gather phase (L1-hot) -> no late
// ef re-read in the epilogue.
// ---------------------------------------------------------------------------
__global__ __launch_bounds__(512, 4) void edge_mfma(
    const float* __restrict__ ef,
    const __bf16* __restrict__ nfb, const __bf16* __restrict__ ub,
    const bf16x8* __restrict__ w1f, const bf16x8* __restrict__ w2f,
    const float* __restrict__ b1, const float* __restrict__ b2,
    const int* __restrict__ src, const int* __restrict__ dst,
    const int* __restrict__ eidx,
    float* __restrict__ out_e, float* __restrict__ agg,
    int E)
{
    __shared__ alignas(16) char lds[49152];
    const int tid = threadIdx.x;
    const int w = tid >> 6, l = tid & 63;
    const int lo = l & 15, hi = l >> 4;
    const long wb = (long)blockIdx.x * 128 + w * 16;   // CSR slot base of wave

    long jL = wb + lo;
    const bool vL = (jL < E);
    const int eA = vL ? eidx[jL] : 0;
    const int srcA = src[eA];
    const int dstA = vL ? dst[eA] : -1;     // -1 isolates invalid rows

    // ---- issue all A-fragment gathers up-front
    bf16x8 afr[8];
#pragma unroll
    for (int kk = 0; kk < 8; ++kk) {
        const int koff = (kk & 1) * 32 + hi * 8;
        const int sec = kk >> 1;
        if (sec == 0) {
            afr[kk] = *(const bf16x8*)(nfb + (size_t)srcA * 64 + koff);
        } else if (sec == 1) {
            int dg = (dstA >= 0) ? dstA : 0;
            afr[kk] = *(const bf16x8*)(nfb + (size_t)dg * 64 + koff);
        } else if (sec == 2) {
            const float* p = ef + (size_t)eA * 64 + koff;
            float4 v0 = *(const float4*)p;
            float4 v1 = *(const float4*)(p + 4);
            bf16x8 t;
            t[0] = (__bf16)v0.x; t[1] = (__bf16)v0.y; t[2] = (__bf16)v0.z; t[3] = (__bf16)v0.w;
            t[4] = (__bf16)v1.x; t[5] = (__bf16)v1.y; t[6] = (__bf16)v1.z; t[7] = (__bf16)v1.w;
            afr[kk] = t;
        } else {
            afr[kk] = *(const bf16x8*)(ub + koff);
        }
    }

    // ---- preload residual ef for the epilogue rows (same rows this wave just
    //      read as fragments -> L1/L2-hot; latency hides under W1 staging)
    int erA[4];
#pragma unroll
    for (int r = 0; r < 4; ++r)
        erA[r] = __shfl(eA, hi * 4 + r);
    float resv[4][4];
#pragma unroll
    for (int r = 0; r < 4; ++r)
#pragma unroll
        for (int nt = 0; nt < 4; ++nt)
            resv[r][nt] = ef[(size_t)erA[r] * 64 + nt * 16 + lo];

    float b1v[8];
#pragma unroll
    for (int nt = 0; nt < 8; ++nt) b1v[nt] = b1[nt * 16 + lo];
    float b2v[4];
#pragma unroll
    for (int nt = 0; nt < 4; ++nt) b2v[nt] = b2[nt * 16 + lo];

    // ---- stage W1 half0 + W2
#pragma unroll
    for (int p = tid; p < 2048; p += 512)
        *(bf16x8*)(lds + p * 16) = w1f[p];
#pragma unroll
    for (int p = tid; p < 1024; p += 512)
        *(bf16x8*)(lds + 32768 + p * 16) = w2f[p];
    __syncthreads();

    // ---- layer 1, kk = 0..3
    f32x4 acc1[8] = {};
#pragma unroll
    for (int kk = 0; kk < 4; ++kk)
#pragma unroll
        for (int nt = 0; nt < 8; ++nt) {
            bf16x8 bfr = *(const bf16x8*)(lds + ((kk * 8 + nt) * 64 + l) * 16);
            acc1[nt] = __builtin_amdgcn_mfma_f32_16x16x32_bf16(afr[kk], bfr, acc1[nt], 0, 0, 0);
        }
    __syncthreads();

    // ---- stage W1 half1
#pragma unroll
    for (int p = tid; p < 2048; p += 512)
        *(bf16x8*)(lds + p * 16) = w1f[2048 + p];
    __syncthreads();

    // ---- layer 1, kk = 4..7
#pragma unroll
    for (int kk = 4; kk < 8; ++kk)
#pragma unroll
        for (int nt = 0; nt < 8; ++nt) {
            bf16x8 bfr = *(const bf16x8*)(lds + (((kk - 4) * 8 + nt) * 64 + l) * 16);
            acc1[nt] = __builtin_amdgcn_mfma_f32_16x16x32_bf16(afr[kk], bfr, acc1[nt], 0, 0, 0);
        }
    __syncthreads();   // all W1 reads done; [0,32K) reusable for h

    // ---- h = relu(acc1+b1) -> per-wave 4KB region
    char* hp = lds + w * 4096;
#pragma unroll
    for (int nt = 0; nt < 8; ++nt) {
        int col = nt * 16 + lo;
#pragma unroll
        for (int r = 0; r < 4; ++r) {
            int row = hi * 4 + r;
            float hv = fmaxf(acc1[nt][r] + b1v[nt], 0.0f);
            *(__bf16*)(hp + SWZ(row, row * 256 + col * 2)) = (__bf16)hv;
        }
    }

    // ---- layer 2
    f32x4 acc2[4] = {};
#pragma unroll
    for (int kk = 0; kk < 4; ++kk) {
        int kb = (kk * 32 + hi * 8) * 2;
        bf16x8 a0 = *(const bf16x8*)(hp + SWZ(lo, lo * 256 + kb));
#pragma unroll
        for (int nt = 0; nt < 4; ++nt) {
            bf16x8 bfr = *(const bf16x8*)(lds + 32768 + ((kk * 4 + nt) * 64 + l) * 16);
            acc2[nt] = __builtin_amdgcn_mfma_f32_16x16x32_bf16(a0, bfr, acc2[nt], 0, 0, 0);
        }
    }

    // ---- fold bias once: acc2 = msg
#pragma unroll
    for (int nt = 0; nt < 4; ++nt)
#pragma unroll
        for (int r = 0; r < 4; ++r)
            acc2[nt][r] += b2v[nt];

    // ---- epilogue A: residual store (registers only)
#pragma unroll
    for (int r = 0; r < 4; ++r) {
        int row = hi * 4 + r;
        if (wb + row >= E) continue;
#pragma unroll
        for (int nt = 0; nt < 4; ++nt)
            out_e[(size_t)erA[r] * 64 + nt * 16 + lo] = acc2[nt][r] + resv[r][nt];
    }

    // ---- epilogue B: dst-segmented reduction -> f32 atomics into agg
    int dn = __shfl(dstA, (l + 1) & 63);
    unsigned long long bal = __ballot(dstA != dn);
    unsigned mm = ((unsigned)bal & 0x7FFFu) | 0x8000u;   // row15 always ends a segment
    int startRow = 0;
    while (mm) {
        int endRow = __ffs(mm);              // segment rows [startRow, endRow)
        int d = __shfl(dstA, startRow);      // uniform
        if (d >= 0) {
            float s0 = 0.f, s1 = 0.f, s2 = 0.f, s3 = 0.f;
#pragma unroll
            for (int r = 0; r < 4; ++r) {
                int row = hi * 4 + r;
                if (row >= startRow && row < endRow) {
                    s0 += acc2[0][r];
                    s1 += acc2[1][r];
                    s2 += acc2[2][r];
                    s3 += acc2[3][r];
                }
            }
            s0 += __shfl_xor(s0, 16); s0 += __shfl_xor(s0, 32);
            s1 += __shfl_xor(s1, 16); s1 += __shfl_xor(s1, 32);
            s2 += __shfl_xor(s2, 16); s2 += __shfl_xor(s2, 32);
            s3 += __shfl_xor(s3, 16); s3 += __shfl_xor(s3, 32);
            if (l < 16) {
                float* ap = agg + (size_t)d * 64;
                atomicAdd(ap + l,      s0);
                atomicAdd(ap + 16 + l, s1);
                atomicAdd(ap + 32 + l, s2);
                atomicAdd(ap + 48 + l, s3);
            }
        }
        startRow = endRow;
        mm &= mm - 1;
    }
}

// ---------------------------------------------------------------------------
// Node MLP, MFMA. K=192 (agg/deg | nfb | u); agg is f32 pre-division sums.
// ---------------------------------------------------------------------------
__global__ __launch_bounds__(512, 4) void node_mfma(
    const float* __restrict__ nf,
    const __bf16* __restrict__ nfb, const __bf16* __restrict__ ub,
    const float* __restrict__ agg, const int* __restrict__ degi,
    const bf16x8* __restrict__ w1f, const bf16x8* __restrict__ w2f,
    const float* __restrict__ b1, const float* __restrict__ b2,
    float* __restrict__ out_n, float* __restrict__ nsum_part,
    int N)
{
    __shared__ alignas(16) char lds[49152];
    const int tid = threadIdx.x;
    const int w = tid >> 6, l = tid & 63;
    const int lo = l & 15, hi = l >> 4;
    const long nb = (long)blockIdx.x * 128 + w * 16;

    long gnL = nb + lo;
    const int gnA = (gnL < N) ? (int)gnL : 0;
    const float inv = 1.0f / fmaxf((float)degi[gnA], 1.0f);

    bf16x8 afr[6];
#pragma unroll
    for (int kk = 0; kk < 6; ++kk) {
        const int koff = (kk & 1) * 32 + hi * 8;
        const int sec = kk >> 1;
        if (sec == 0) {
            const float* p = agg + (size_t)gnA * 64 + koff;
            float4 v0 = *(const float4*)p;
            float4 v1 = *(const float4*)(p + 4);
            bf16x8 t;
            t[0] = (__bf16)(v0.x * inv); t[1] = (__bf16)(v0.y * inv);
            t[2] = (__bf16)(v0.z * inv); t[3] = (__bf16)(v0.w * inv);
            t[4] = (__bf16)(v1.x * inv); t[5] = (__bf16)(v1.y * inv);
            t[6] = (__bf16)(v1.z * inv); t[7] = (__bf16)(v1.w * inv);
            afr[kk] = t;
        } else if (sec == 1) {
            afr[kk] = *(const bf16x8*)(nfb + (size_t)gnA * 64 + koff);
        } else {
            afr[kk] = *(const bf16x8*)(ub + koff);
        }
    }

    float b1v[8];
#pragma unroll
    for (int nt = 0; nt < 8; ++nt) b1v[nt] = b1[nt * 16 + lo];
    float b2v[4];
#pragma unroll
    for (int nt = 0; nt < 4; ++nt) b2v[nt] = b2[nt * 16 + lo];

    // stage W1n half0 (24 frags) + W2
#pragma unroll
    for (int p = tid; p < 1536; p += 512)
        *(bf16x8*)(lds + p * 16) = w1f[p];
#pragma unroll
    for (int p = tid; p < 1024; p += 512)
        *(bf16x8*)(lds + 32768 + p * 16) = w2f[p];
    __syncthreads();

    f32x4 acc1[8] = {};
#pragma unroll
    for (int kk = 0; kk < 3; ++kk)
#pragma unroll
        for (int nt = 0; nt < 8; ++nt) {
            bf16x8 bfr = *(const bf16x8*)(lds + ((kk * 8 + nt) * 64 + l) * 16);
            acc1[nt] = __builtin_amdgcn_mfma_f32_16x16x32_bf16(afr[kk], bfr, acc1[nt], 0, 0, 0);
        }
    __syncthreads();

#pragma unroll
    for (int p = tid; p < 1536; p += 512)
        *(bf16x8*)(lds + p * 16) = w1f[1536 + p];
    __syncthreads();

#pragma unroll
    for (int kk = 3; kk < 6; ++kk)
#pragma unroll
        for (int nt = 0; nt < 8; ++nt) {
            bf16x8 bfr = *(const bf16x8*)(lds + (((kk - 3) * 8 + nt) * 64 + l) * 16);
            acc1[nt] = __builtin_amdgcn_mfma_f32_16x16x32_bf16(afr[kk], bfr, acc1[nt], 0, 0, 0);
        }
    __syncthreads();

    char* hp = lds + w * 4096;
#pragma unroll
    for (int nt = 0; nt < 8; ++nt) {
        int col = nt * 16 + lo;
#pragma unroll
        for (int r = 0; r < 4; ++r) {
            int row = hi * 4 + r;
            float hv = fmaxf(acc1[nt][r] + b1v[nt], 0.0f);
            *(__bf16*)(hp + SWZ(row, row * 256 + col * 2)) = (__bf16)hv;
        }
    }

    f32x4 acc2[4] = {};
#pragma unroll
    for (int kk = 0; kk < 4; ++kk) {
        int kb = (kk * 32 + hi * 8) * 2;
        bf16x8 a0 = *(const bf16x8*)(hp + SWZ(lo, lo * 256 + kb));
#pragma unroll
        for (int nt = 0; nt < 4; ++nt) {
            bf16x8 bfr = *(const bf16x8*)(lds + 32768 + ((kk * 4 + nt) * 64 + l) * 16);
            acc2[nt] = __builtin_amdgcn_mfma_f32_16x16x32_bf16(a0, bfr, acc2[nt], 0, 0, 0);
        }
    }

    float vsum[4] = {0.f, 0.f, 0.f, 0.f};
#pragma unroll
    for (int r = 0; r < 4; ++r) {
        long gn = nb + hi * 4 + r;
        if (gn >= N) continue;
        int gni = (int)gn;
#pragma unroll
        for (int nt = 0; nt < 4; ++nt) {
            int col = nt * 16 + lo;
            float msg = acc2[nt][r] + b2v[nt];
            out_n[(size_t)gni * 64 + col] = msg + nf[(size_t)gni * 64 + col];
            vsum[nt] += msg;
        }
    }
#pragma unroll
    for (int nt = 0; nt < 4; ++nt) {
        float v = vsum[nt];
        v += __shfl_xor(v, 16);
        v += __shfl_xor(v, 32);
        if (l < 16) nsum_part[((size_t)blockIdx.x * 8 + w) * 64 + nt * 16 + l] = v;
    }
}

// ---------------------------------------------------------------------------
// reduce_two: blocks [0,NBA) sum agg rows -> edge_sum;
//             blocks [NBA,NBA+NBB) sum nsum_part rows -> node_sum.
// ---------------------------------------------------------------------------
__global__ __launch_bounds__(256) void reduce_two(
    const float* __restrict__ aggIn, float* __restrict__ edge_sum, int RA, int NBA,
    const float* __restrict__ nsumIn, float* __restrict__ node_sum, int RB, int NBB)
{
    const float* in; float* out; int R, rb, nb;
    if ((int)blockIdx.x < NBA) { in = aggIn;  out = edge_sum; R = RA; rb = blockIdx.x;       nb = NBA; }
    else                       { in = nsumIn; out = node_sum; R = RB; rb = blockIdx.x - NBA; nb = NBB; }
    int col = threadIdx.x & 63;
    float s = 0.f;
    for (int r = rb * 4 + (threadIdx.x >> 6); r < R; r += nb * 4)
        s += in[(size_t)r * 64 + col];
    __shared__ float sm[256];
    sm[threadIdx.x] = s;
    __syncthreads();
    if (threadIdx.x < 64) {
        float v = sm[threadIdx.x] + sm[threadIdx.x + 64] + sm[threadIdx.x + 128] + sm[threadIdx.x + 192];
        atomicAdd(&out[threadIdx.x], v);
    }
}

// ---------------------------------------------------------------------------
// Global MLP: single block.
// ---------------------------------------------------------------------------
__global__ __launch_bounds__(128) void global_kernel(
    const float* __restrict__ u,
    const float* __restrict__ W1, const float* __restrict__ b1,
    const float* __restrict__ W2, const float* __restrict__ b2,
    const float* __restrict__ node_sum, const float* __restrict__ edge_sum,
    float* __restrict__ out_u, int N, int E)
{
    __shared__ float gm[192];
    __shared__ float h[128];
    int tid = threadIdx.x;
    if (tid < 64) {
        gm[tid]       = node_sum[tid] / (float)N;
        gm[64 + tid]  = edge_sum[tid] / (float)E;
        gm[128 + tid] = u[tid];
    }
    __syncthreads();
    float a = b1[tid];
    for (int k = 0; k < 192; ++k) a = fmaf(gm[k], W1[k * 128 + tid], a);
    h[tid] = fmaxf(a, 0.f);
    __syncthreads();
    if (tid < 64) {
        float o = b2[tid];
        for (int k = 0; k < 128; ++k) o = fmaf(h[k], W2[k * 64 + tid], o);
        out_u[tid] = o + u[tid];
    }
}

extern "C" void kernel_launch(void* const* d_in, const int* in_sizes, int n_in,
                              void* d_out, int out_size, void* d_ws, size_t ws_size,
                              hipStream_t stream) {
    const float* nf  = (const float*)d_in[0];
    const float* ef  = (const float*)d_in[1];
    const float* u   = (const float*)d_in[2];
    const float* eW1 = (const float*)d_in[3];
    const float* eb1 = (const float*)d_in[4];
    const float* eW2 = (const float*)d_in[5];
    const float* eb2 = (const float*)d_in[6];
    const float* nW1 = (const float*)d_in[7];
    const float* nb1 = (const float*)d_in[8];
    const float* nW2 = (const float*)d_in[9];
    const float* nb2 = (const float*)d_in[10];
    const float* gW1 = (const float*)d_in[11];
    const float* gb1 = (const float*)d_in[12];
    const float* gW2 = (const float*)d_in[13];
    const float* gb2 = (const float*)d_in[14];
    const int*   src = (const int*)d_in[15];
    const int*   dst = (const int*)d_in[16];

    const int N = in_sizes[0] / 64;
    const int E = in_sizes[1] / 64;
    const int EDGE_BLOCKS = (E + 127) / 128;
    const int NODE_BLOCKS = (N + 127) / 128;
    const int SCAN_NB = (N + 255) / 256;       // <= 256 for N <= 65536

    char* ws = (char*)d_ws;
    size_t off_b = 0;
    auto alloc = [&](size_t bytes) { size_t c = off_b; off_b += (bytes + 255) & ~(size_t)255; return c; };

    // zeroed region first: degi | cursor | edge_sum | node_sum | agg
    int*    degi     = (int*)(ws + alloc((size_t)N * 4));
    int*    cursor   = (int*)(ws + alloc((size_t)N * 4));
    float*  edge_sum = (float*)(ws + alloc(256));
    float*  node_sum = (float*)(ws + alloc(256));
    float*  agg      = (float*)(ws + alloc((size_t)N * 64 * 4));
    size_t  zero_bytes = off_b;
    int*    offs     = (int*)(ws + alloc((size_t)N * 4));
    int*    bsum     = (int*)(ws + alloc((size_t)SCAN_NB * 4));
    int*    bofs     = (int*)(ws + alloc((size_t)SCAN_NB * 4));
    int*    eidx     = (int*)(ws + alloc((size_t)E * 4));
    float*  nsum_part= (float*)(ws + alloc((size_t)NODE_BLOCKS * 8 * 64 * 4));
    __bf16* nfb   = (__bf16*)(ws + alloc((size_t)N * 64 * 2));
    __bf16* ub    = (__bf16*)(ws + alloc(256));
    __bf16* w1e_f = (__bf16*)(ws + alloc(32768 * 2));
    __bf16* w2e_f = (__bf16*)(ws + alloc(8192 * 2));
    __bf16* w1n_f = (__bf16*)(ws + alloc(24576 * 2));
    __bf16* w2n_f = (__bf16*)(ws + alloc(8192 * 2));

    float* out_n = (float*)d_out;
    float* out_e = out_n + (size_t)N * 64;
    float* out_u = out_e + (size_t)E * 64;

    const int B_NF = (N * 16 + 255) / 256;     // N*64/4 threads
    const int B_W  = (73792 + 255) / 256;
    const int B_H  = (E + 255) / 256;

    hipMemsetAsync(d_ws, 0, zero_bytes, stream);
    prep_all<<<B_NF + B_W + B_H, 256, 0, stream>>>(
        nf, nfb, N * 64, eW1, eW2, nW1, nW2, u,
        w1e_f, w2e_f, w1n_f, w2n_f, ub, dst, degi, E, B_NF, B_W);
    scan_local<<<SCAN_NB, 256, 0, stream>>>(degi, offs, bsum, N);
    scan_blocks<<<1, 256, 0, stream>>>(bsum, bofs, SCAN_NB);
    scan_add<<<SCAN_NB, 256, 0, stream>>>(offs, bofs, N);
    fill_kernel<<<(E + 255) / 256, 256, 0, stream>>>(dst, offs, cursor, eidx, E);
    edge_mfma<<<EDGE_BLOCKS, 512, 0, stream>>>(
        ef, nfb, ub, (const bf16x8*)w1e_f, (const bf16x8*)w2e_f, eb1, eb2,
        src, dst, eidx, out_e, agg, E);
    node_mfma<<<NODE_BLOCKS, 512, 0, stream>>>(
        nf, nfb, ub, agg, degi, (const bf16x8*)w1n_f, (const bf16x8*)w2n_f,
        nb1, nb2, out_n, nsum_part, N);
    reduce_two<<<128 + 16, 256, 0, stream>>>(
        agg, edge_sum, N, 128, nsum_part, node_sum, NODE_BLOCKS * 8, 16);
    global_kernel<<<1, 128, 0, stream>>>(
        u, gW1, gb1, gW2, gb2, node_sum, edge_sum, out_u, N, E);
}